// Round 8
// baseline (585.945 us; speedup 1.0000x reference)
//
#include <hip/hip_runtime.h>
#include <math.h>

#define NB 16
#define N0 4096
#define NE 524288

// ---------------- CSR build (layer 0, atomic int cursor only) ----------------

static __global__ void k_count(const int* __restrict__ dst, int* __restrict__ cnt) {
  int e = blockIdx.x * 256 + threadIdx.x;
  if (e >= NE) return;
  atomicAdd(&cnt[dst[e]], 1);
}

static __global__ void k_fill0(const int* __restrict__ src, const int* __restrict__ dst,
                               int* __restrict__ cursor, int* __restrict__ list) {
  int e = blockIdx.x * 256 + threadIdx.x;
  if (e >= NE) return;
  int d = dst[e];
  int slot = atomicAdd(&cursor[d], 1);
  list[slot] = src[e];
}

// ---------------- exclusive scan: single block, 1024 threads, n = m*1024 ----------------

static __global__ __launch_bounds__(1024) void k_scan_one(const int* __restrict__ in,
                                                          int* __restrict__ out,
                                                          int* __restrict__ out2, int n) {
  __shared__ int ts[1024];
  int t = threadIdx.x;
  int E = n >> 10;
  int base = t * E;
  int loc = 0;
#pragma unroll 4
  for (int j = 0; j < E; ++j) loc += in[base + j];
  ts[t] = loc;
  __syncthreads();
  for (int off = 1; off < 1024; off <<= 1) {
    int v = (t >= off) ? ts[t - off] : 0;
    __syncthreads();
    ts[t] += v;
    __syncthreads();
  }
  int run = ts[t] - loc;
  if (out2) {
    for (int j = 0; j < E; ++j) {
      out[base + j] = run;
      out2[base + j] = run;
      run += in[base + j];
    }
  } else {
    for (int j = 0; j < E; ++j) {
      out[base + j] = run;
      run += in[base + j];
    }
  }
}

// ---------------- CSR compaction after pooling (no atomics) ----------------

static __global__ void k_newcount(const int* __restrict__ perm, const int* __restrict__ offs,
                                  const int* __restrict__ cnt, const int* __restrict__ list,
                                  const int* __restrict__ newidx, int* __restrict__ ncnt,
                                  int newn) {
  int nn = blockIdx.x * 256 + threadIdx.x;
  if (nn >= newn) return;
  int old = perm[nn];
  int st = offs[old], c = cnt[old];
  int cc = 0;
  for (int j = 0; j < c; ++j) cc += (newidx[list[st + j]] >= 0);
  ncnt[nn] = cc;
}

static __global__ void k_newfill(const int* __restrict__ perm, const int* __restrict__ offs,
                                 const int* __restrict__ cnt, const int* __restrict__ list,
                                 const int* __restrict__ newidx, const int* __restrict__ noffs,
                                 int* __restrict__ nlist, int newn) {
  int nn = blockIdx.x * 256 + threadIdx.x;
  if (nn >= newn) return;
  int old = perm[nn];
  int st = offs[old], c = cnt[old];
  int pos = noffs[nn];
  for (int j = 0; j < c; ++j) {
    int s2 = newidx[list[st + j]];
    if (s2 >= 0) nlist[pos++] = s2;
  }
}

// ---------------- p-norms (all 6 layers, once) ----------------

static __global__ void k_pnorm(const float* __restrict__ p0, const float* __restrict__ p1,
                               const float* __restrict__ p2, const float* __restrict__ p3,
                               const float* __restrict__ p4, const float* __restrict__ p5,
                               float* __restrict__ pnbuf) {
  const float* pp = p0;
  switch (blockIdx.x) {
    case 1: pp = p1; break;
    case 2: pp = p2; break;
    case 3: pp = p3; break;
    case 4: pp = p4; break;
    case 5: pp = p5; break;
    default: break;
  }
  double v = (double)pp[threadIdx.x];
  v *= v;
#pragma unroll
  for (int off = 1; off < 64; off <<= 1) v += __shfl_xor(v, off);
  if (threadIdx.x == 0) pnbuf[blockIdx.x] = (float)(1.0 / sqrt(v));
}

// ---------------- SAGE ----------------

static __global__ void k_sage_gather2(const float* __restrict__ x, const int* __restrict__ offs,
                                      const int* __restrict__ cnt, const int* __restrict__ list,
                                      float* __restrict__ mean, int ntot) {
  int v = blockIdx.x * 256 + threadIdx.x;
  if (v >= ntot) return;
  int st = offs[v], c = cnt[v];
  float s0 = 0.f, s1 = 0.f;
  for (int j = 0; j < c; ++j) {
    int s = list[st + j];
    s0 += x[s * 2 + 0];
    s1 += x[s * 2 + 1];
  }
  float inv = 1.0f / fmaxf((float)c, 1.0f);
  mean[v * 2 + 0] = s0 * inv;
  mean[v * 2 + 1] = s1 * inv;
}

// layer-0 SAGE (DIN=2) + fused score (wave butterfly, double)
static __global__ void k_sage0(const float* __restrict__ x, const float* __restrict__ mean,
                               const float* __restrict__ wl, const float* __restrict__ blv,
                               const float* __restrict__ wr, const float* __restrict__ pvec,
                               const float* __restrict__ pnbuf, float* __restrict__ h,
                               float* __restrict__ score, int ntot) {
  __shared__ float wlT[2][65], wrT[2][65];
  if (threadIdx.x < 128) {
    int o = threadIdx.x >> 1, d = threadIdx.x & 1;
    wlT[d][o] = wl[o * 2 + d];
    wrT[d][o] = wr[o * 2 + d];
  }
  __syncthreads();
  int o = threadIdx.x & 63, vl = threadIdx.x >> 6;
  int base = blockIdx.x * 16 + vl * 4;
  float pn = pnbuf[0];
  float psl = pvec[o];
#pragma unroll
  for (int r = 0; r < 4; ++r) {
    int v = base + r;
    if (v >= ntot) break;
    float acc = blv[o] + mean[v * 2 + 0] * wlT[0][o] + mean[v * 2 + 1] * wlT[1][o] +
                x[v * 2 + 0] * wrT[0][o] + x[v * 2 + 1] * wrT[1][o];
    float hval = fmaxf(acc, 0.0f);
    h[(size_t)v * 64 + o] = hval;
    double sc = (double)hval * (double)psl;
#pragma unroll
    for (int off = 1; off < 64; off <<= 1) sc += __shfl_xor(sc, off);
    if (o == 0) score[v] = (float)sc * pn;
  }
}

// Fused SAGE DIN=64: in-kernel mean gather (16-node ILP) -> swizzled LDS A-tile,
// tiled GEMM 4x4/thread, bias+relu+score epilogue.
static __global__ __launch_bounds__(256) void k_sage_mm(
    const float* __restrict__ x, const int* __restrict__ offs, const int* __restrict__ cnt,
    const int* __restrict__ list, const float* __restrict__ wl, const float* __restrict__ blv,
    const float* __restrict__ wr, const float* __restrict__ pvec,
    const float* __restrict__ pnbuf, int pidx, float* __restrict__ h,
    float* __restrict__ score) {
  __shared__ float smem[16384];
  __shared__ float psh[64], bsh[64];
  float* xT = smem;
  float* mT = smem + 4096;
  float* wlT = smem + 8192;
  float* wrT = smem + 12288;
  int t = threadIdx.x;
  size_t nb = blockIdx.x;

  const float4* wl4 = (const float4*)wl;
  const float4* wr4 = (const float4*)wr;
  for (int i4 = t; i4 < 1024; i4 += 256) {
    int o = i4 >> 4, db = (i4 & 15) << 2;
    float4 L = wl4[i4], R = wr4[i4];
    float Lv[4] = {L.x, L.y, L.z, L.w}, Rv[4] = {R.x, R.y, R.z, R.w};
    int og = o >> 2, o3 = o & 3;
#pragma unroll
    for (int j = 0; j < 4; ++j) {
      int d = db + j;
      int col = ((og ^ (d & 15)) << 2) | o3;
      wlT[(d << 6) + col] = Lv[j];
      wrT[(d << 6) + col] = Rv[j];
    }
  }
  if (t < 64) {
    psh[t] = pvec[t];
    bsh[t] = blv[t];
  }
  const float4* x4 = (const float4*)(x + nb * 4096);
  for (int i = t; i < 1024; i += 256) {
    int node = i >> 4, db = (i & 15) << 2;
    float4 a = x4[i];
    float av[4] = {a.x, a.y, a.z, a.w};
    int ng = node >> 2, n0 = node & 3;
#pragma unroll
    for (int j = 0; j < 4; ++j) {
      int d = db + j;
      xT[(d << 6) + (((ng ^ (d & 15)) << 2) | n0)] = av[j];
    }
  }
  // mean gather: wave w handles nodes w*16..w*16+15 with 16-way load ILP
  {
    int lane = t & 63, w = t >> 6;
    int stq[16], cq[16];
    float accq[16];
    int cmax = 0;
#pragma unroll
    for (int q = 0; q < 16; ++q) {
      int gv = (int)nb * 64 + w * 16 + q;
      stq[q] = offs[gv];
      cq[q] = cnt[gv];
      accq[q] = 0.f;
      cmax = max(cmax, cq[q]);
    }
    for (int j = 0; j < cmax; ++j) {
#pragma unroll
      for (int q = 0; q < 16; ++q) {
        if (j < cq[q]) accq[q] += x[(size_t)list[stq[q] + j] * 64 + lane];
      }
    }
#pragma unroll
    for (int q = 0; q < 16; ++q) {
      int node = w * 16 + q;
      float mval = accq[q] * (1.0f / fmaxf((float)cq[q], 1.0f));
      int col = (((node >> 2) ^ (lane & 15)) << 2) | (node & 3);
      mT[(lane << 6) + col] = mval;
    }
  }
  __syncthreads();

  int tx = t & 15, ty = t >> 4;
  float acc[4][4] = {};
#pragma unroll 4
  for (int k = 0; k < 64; ++k) {
    int s = k & 15;
    int ca = (tx ^ s) << 2, cb = (ty ^ s) << 2;
    const float4 a = *(const float4*)&xT[(k << 6) + ca];
    const float4 m = *(const float4*)&mT[(k << 6) + ca];
    const float4 L = *(const float4*)&wlT[(k << 6) + cb];
    const float4 R = *(const float4*)&wrT[(k << 6) + cb];
    float A[4] = {a.x, a.y, a.z, a.w}, M[4] = {m.x, m.y, m.z, m.w};
    float Lv[4] = {L.x, L.y, L.z, L.w}, Rv[4] = {R.x, R.y, R.z, R.w};
#pragma unroll
    for (int r = 0; r < 4; ++r)
#pragma unroll
      for (int c = 0; c < 4; ++c) acc[r][c] += M[r] * Lv[c] + A[r] * Rv[c];
  }

  float pn = pnbuf[pidx];
  float hv[4][4];
  double sp[4];
#pragma unroll
  for (int r = 0; r < 4; ++r) {
    sp[r] = 0.0;
#pragma unroll
    for (int c = 0; c < 4; ++c) {
      float v = fmaxf(acc[r][c] + bsh[(ty << 2) + c], 0.0f);
      hv[r][c] = v;
      sp[r] += (double)v * (double)psh[(ty << 2) + c];
    }
  }
  __syncthreads();  // reuse smem
  float* hT = smem;                       // stride 68, swizzled col
  double* sred = (double*)(smem + 8192);  // [16][64]
#pragma unroll
  for (int r = 0; r < 4; ++r) {
    int node = (tx << 2) + r;
    int nk = node & 15;
#pragma unroll
    for (int c = 0; c < 4; ++c) hT[node * 68 + (((ty ^ nk) << 2) | c)] = hv[r][c];
    sred[(ty << 6) + node] = sp[r];
  }
  __syncthreads();
  float4* h4 = (float4*)(h + nb * 4096);
  for (int i = t; i < 1024; i += 256) {
    int node = i >> 4, q = i & 15;
    h4[i] = *(const float4*)&hT[node * 68 + ((q ^ (node & 15)) << 2)];
  }
  if (t < 64) {
    double ssum = 0.0;
    for (int g = 0; g < 16; ++g) ssum += sred[(g << 6) + t];
    score[nb * 64 + t] = (float)ssum * pn;
  }
}

// ---------------- GCN ----------------

static __global__ __launch_bounds__(256) void k_gcn_mm(const float* __restrict__ x,
                                                       const float* __restrict__ w,
                                                       float* __restrict__ h1) {
  __shared__ float smem[8192];
  float* xT = smem;
  float* wT = smem + 4096;
  int t = threadIdx.x;
  size_t nb = blockIdx.x;
  const float4* w4 = (const float4*)w;
  for (int i4 = t; i4 < 1024; i4 += 256) {
    int o = i4 >> 4, db = (i4 & 15) << 2;
    float4 W = w4[i4];
    float Wv[4] = {W.x, W.y, W.z, W.w};
    int og = o >> 2, o3 = o & 3;
#pragma unroll
    for (int j = 0; j < 4; ++j) {
      int d = db + j;
      wT[(d << 6) + (((og ^ (d & 15)) << 2) | o3)] = Wv[j];
    }
  }
  const float4* x4 = (const float4*)(x + nb * 4096);
  for (int i = t; i < 1024; i += 256) {
    int node = i >> 4, db = (i & 15) << 2;
    float4 a = x4[i];
    float av[4] = {a.x, a.y, a.z, a.w};
    int ng = node >> 2, n0 = node & 3;
#pragma unroll
    for (int j = 0; j < 4; ++j) {
      int d = db + j;
      xT[(d << 6) + (((ng ^ (d & 15)) << 2) | n0)] = av[j];
    }
  }
  __syncthreads();
  int tx = t & 15, ty = t >> 4;
  float acc[4][4] = {};
#pragma unroll 4
  for (int k = 0; k < 64; ++k) {
    int s = k & 15;
    const float4 a = *(const float4*)&xT[(k << 6) + ((tx ^ s) << 2)];
    const float4 W = *(const float4*)&wT[(k << 6) + ((ty ^ s) << 2)];
    float A[4] = {a.x, a.y, a.z, a.w}, Wv[4] = {W.x, W.y, W.z, W.w};
#pragma unroll
    for (int r = 0; r < 4; ++r)
#pragma unroll
      for (int c = 0; c < 4; ++c) acc[r][c] += A[r] * Wv[c];
  }
  __syncthreads();
  float* hT = smem;  // stride 68
#pragma unroll
  for (int r = 0; r < 4; ++r) {
    int node = (tx << 2) + r;
    int nk = node & 15;
#pragma unroll
    for (int c = 0; c < 4; ++c) hT[node * 68 + (((ty ^ nk) << 2) | c)] = acc[r][c];
  }
  __syncthreads();
  float4* h4 = (float4*)(h1 + nb * 4096);
  for (int i = t; i < 1024; i += 256) {
    int node = i >> 4, q = i & 15;
    h4[i] = *(const float4*)&hT[node * 68 + ((q ^ (node & 15)) << 2)];
  }
}

// fused: normalized gather + self term + bias + relu + score
static __global__ void k_gcn_gather(const float* __restrict__ h1, const int* __restrict__ offs,
                                    const int* __restrict__ cnt, const int* __restrict__ list,
                                    const float* __restrict__ b, const float* __restrict__ pvec,
                                    const float* __restrict__ pnbuf, int pidx,
                                    float* __restrict__ h, float* __restrict__ score, int ntot) {
  int lane = threadIdx.x & 63, vl = threadIdx.x >> 6;
  int v = blockIdx.x * 4 + vl;
  if (v >= ntot) return;
  int st = offs[v], c = cnt[v];
  float degv = 1.0f + (float)c;
  float ivd = 1.0f / sqrtf(degv);
  float acc = 0.f;
  for (int j = 0; j < c; ++j) {
    int s = list[st + j];
    float nrm = (1.0f / sqrtf(1.0f + (float)cnt[s])) * ivd;
    acc += h1[(size_t)s * 64 + lane] * nrm;
  }
  float outv = fmaxf(acc + h1[(size_t)v * 64 + lane] * (1.0f / degv) + b[lane], 0.0f);
  h[(size_t)v * 64 + lane] = outv;
  double sc = (double)outv * (double)pvec[lane];
#pragma unroll
  for (int off = 1; off < 64; off <<= 1) sc += __shfl_xor(sc, off);
  if (lane == 0) score[v] = (float)sc * pnbuf[pidx];
}

// ---------------- TopK pool: chunk bitonic (<=1024) + merge-path ----------------

static __global__ void k_chunksort(const float* __restrict__ score,
                                   unsigned long long* __restrict__ runs, int n_per, int k,
                                   int* __restrict__ newidx, int* __restrict__ perm, int single) {
  extern __shared__ unsigned long long sk[];
  int CH = blockDim.x;
  int g0 = blockIdx.x * CH;
  int b = g0 / n_per;
  int i = threadIdx.x;
  int gi = g0 + i;
  int li = gi - b * n_per;
  unsigned u = __float_as_uint(score[gi]);
  unsigned s = (u & 0x80000000u) ? u : ~(u | 0x80000000u);
  sk[i] = ((unsigned long long)s << 32) | (unsigned)li;
  __syncthreads();
  for (int ksz = 2; ksz <= CH; ksz <<= 1) {
    for (int j = ksz >> 1; j > 0; j >>= 1) {
      int ixj = i ^ j;
      if (ixj > i) {
        unsigned long long a = sk[i], c = sk[ixj];
        bool up = ((i & ksz) == 0);
        if ((a > c) == up) {
          sk[i] = c;
          sk[ixj] = a;
        }
      }
      __syncthreads();
    }
  }
  if (!single) {
    runs[gi] = sk[i];
  } else {
    int r = i;
    int idx = (int)(sk[r] & 0xFFFFFFFFu);
    int gidx = b * n_per + idx;
    if (r < k) {
      perm[b * k + r] = gidx;
      newidx[gidx] = b * k + r;
    } else {
      newidx[gidx] = -1;
    }
  }
}

static __global__ void k_merge(const unsigned long long* __restrict__ in,
                               unsigned long long* __restrict__ out, int L, int ntot, int n_per,
                               int k, int* __restrict__ newidx, int* __restrict__ perm,
                               int final) {
  int g = blockIdx.x * 256 + threadIdx.x;
  if (g >= ntot) return;
  unsigned long long key = in[g];
  int pair = g / (2 * L);
  int base = pair * 2 * L;
  int t = g - base;
  const unsigned long long* sib;
  int p;
  if (t < L) {
    sib = in + base + L;
    p = t;
  } else {
    sib = in + base;
    p = t - L;
  }
  int lo = 0, hi = L;
  while (lo < hi) {
    int mid = (lo + hi) >> 1;
    lo = (sib[mid] < key) ? mid + 1 : lo;
    hi = (sib[mid] < key) ? hi : mid;
  }
  int pos = p + lo;
  if (!final) {
    out[base + pos] = key;
  } else {
    int b = base / n_per;
    int idx = (int)(key & 0xFFFFFFFFu);
    int gidx = b * n_per + idx;
    if (pos < k) {
      perm[b * k + pos] = gidx;
      newidx[gidx] = b * k + pos;
    } else {
      newidx[gidx] = -1;
    }
  }
}

// ---------------- fused gather (tanh-scale) + readout partials ----------------
// block = 64 new nodes, 1024 threads; writes xnew + per-chunk max/sum partials.

static __global__ __launch_bounds__(1024) void k_gather_ro(
    const float* __restrict__ h, const float* __restrict__ score, const int* __restrict__ perm,
    float* __restrict__ xnew, float* __restrict__ pmax, float* __restrict__ psum) {
  __shared__ float tile[64 * 68];
  __shared__ float pm[16][65], ps[16][65];
  int t = threadIdx.x;
  int node = t >> 4, q = t & 15;
  int nn = blockIdx.x * 64 + node;
  int old = perm[nn];
  float tm = tanhf(score[old]);
  float4 v = *(const float4*)&h[(size_t)old * 64 + q * 4];
  v.x *= tm;
  v.y *= tm;
  v.z *= tm;
  v.w *= tm;
  *(float4*)&xnew[(size_t)nn * 64 + q * 4] = v;
  *(float4*)&tile[node * 68 + ((q ^ (node & 15)) << 2)] = v;
  __syncthreads();
  int slot = t >> 6, d = t & 63;
  int q2 = d >> 2, i3 = d & 3;
  float m = -INFINITY, s = 0.f;
#pragma unroll
  for (int r = 0; r < 4; ++r) {
    int nd = slot * 4 + r;
    float val = tile[nd * 68 + (((q2 ^ (nd & 15)) << 2) | i3)];
    m = fmaxf(m, val);
    s += val;
  }
  pm[slot][d] = m;
  ps[slot][d] = s;
  __syncthreads();
  if (t < 64) {
    float mm = -INFINITY, ss = 0.f;
#pragma unroll
    for (int sl = 0; sl < 16; ++sl) {
      mm = fmaxf(mm, pm[sl][t]);
      ss += ps[sl][t];
    }
    pmax[(size_t)blockIdx.x * 64 + t] = mm;
    psum[(size_t)blockIdx.x * 64 + t] = ss;
  }
}

static __global__ void k_readout_comb(const float* __restrict__ pmax,
                                      const float* __restrict__ psum, float* __restrict__ z,
                                      int k, int nch) {
  int b = blockIdx.x, d = threadIdx.x;
  float m = -INFINITY, s = 0.0f;
  for (int c = 0; c < nch; ++c) {
    m = fmaxf(m, pmax[((size_t)b * nch + c) * 64 + d]);
    s += psum[((size_t)b * nch + c) * 64 + d];
  }
  z[b * 128 + d] += m;
  z[b * 128 + 64 + d] += s / (float)k;
}

// ---------------- MLP + softmax ----------------

static __global__ void k_mlp(const float* __restrict__ z, const float* __restrict__ lw1,
                             const float* __restrict__ lb1, const float* __restrict__ lw2,
                             const float* __restrict__ lb2, const float* __restrict__ lw3,
                             const float* __restrict__ lb3, float* __restrict__ out) {
  __shared__ float zs[128], t1[128], t2[64], t3[256], red[256];
  int b = blockIdx.x, tid = threadIdx.x;
  if (tid < 128) zs[tid] = z[b * 128 + tid];
  __syncthreads();
  if (tid < 128) {
    double a = 0.0;
    for (int d = 0; d < 128; ++d) a += (double)lw1[tid * 128 + d] * (double)zs[d];
    t1[tid] = fmaxf((float)a + lb1[tid], 0.0f);
  }
  __syncthreads();
  if (tid < 64) {
    double a = 0.0;
    for (int d = 0; d < 128; ++d) a += (double)lw2[tid * 128 + d] * (double)t1[d];
    t2[tid] = fmaxf((float)a + lb2[tid], 0.0f);
  }
  __syncthreads();
  {
    double a = 0.0;
    for (int d = 0; d < 64; ++d) a += (double)lw3[tid * 64 + d] * (double)t2[d];
    t3[tid] = (float)a + lb3[tid];
  }
  __syncthreads();
  red[tid] = t3[tid];
  __syncthreads();
  for (int s = 128; s > 0; s >>= 1) {
    if (tid < s) red[tid] = fmaxf(red[tid], red[tid + s]);
    __syncthreads();
  }
  float mx = red[0];
  __syncthreads();
  float e = expf(t3[tid] - mx);
  red[tid] = e;
  __syncthreads();
  for (int s = 128; s > 0; s >>= 1) {
    if (tid < s) red[tid] += red[tid + s];
    __syncthreads();
  }
  out[b * 256 + tid] = e / red[0];
}

// ---------------- launch ----------------

extern "C" void kernel_launch(void* const* d_in, const int* in_sizes, int n_in,
                              void* d_out, int out_size, void* d_ws, size_t ws_size,
                              hipStream_t stream) {
  const float* x0 = (const float*)d_in[0];
  const int* esrc0 = (const int*)d_in[1];
  const int* edst0 = (const int*)d_in[2];
  const float* WL[3] = {(const float*)d_in[3], (const float*)d_in[6], (const float*)d_in[9]};
  const float* BL[3] = {(const float*)d_in[4], (const float*)d_in[7], (const float*)d_in[10]};
  const float* WR[3] = {(const float*)d_in[5], (const float*)d_in[8], (const float*)d_in[11]};
  const float* WG[3] = {(const float*)d_in[12], (const float*)d_in[14], (const float*)d_in[16]};
  const float* BG[3] = {(const float*)d_in[13], (const float*)d_in[15], (const float*)d_in[17]};
  const float* P[6] = {(const float*)d_in[18], (const float*)d_in[19], (const float*)d_in[20],
                       (const float*)d_in[21], (const float*)d_in[22], (const float*)d_in[23]};
  const float* lw1 = (const float*)d_in[24];
  const float* lb1 = (const float*)d_in[25];
  const float* lw2 = (const float*)d_in[26];
  const float* lb2 = (const float*)d_in[27];
  const float* lw3 = (const float*)d_in[28];
  const float* lb3 = (const float*)d_in[29];

  char* ws = (char*)d_ws;
  size_t off = 0;
  auto alloc = [&](size_t bytes) -> void* {
    void* p = ws + off;
    off += (bytes + 255) & ~(size_t)255;
    return p;
  };
  float* hA = (float*)alloc((size_t)65536 * 64 * 4);
  float* hB = (float*)alloc((size_t)32768 * 64 * 4);
  float* mean = (float*)alloc((size_t)65536 * 2 * 4);
  float* tmp = (float*)alloc((size_t)8192 * 64 * 4);
  float* score = (float*)alloc((size_t)65536 * 4);
  int* newidx = (int*)alloc((size_t)65536 * 4);
  int* perm = (int*)alloc((size_t)32768 * 4);
  int* cntA = (int*)alloc((size_t)65536 * 4);
  int* cntB = (int*)alloc((size_t)65536 * 4);
  int* offsA = (int*)alloc((size_t)65536 * 4);
  int* offsB = (int*)alloc((size_t)65536 * 4);
  int* cursor = (int*)alloc((size_t)65536 * 4);
  int* listA = (int*)alloc((size_t)NE * 4);
  int* listB = (int*)alloc((size_t)NE * 4);
  float* z = (float*)alloc((size_t)16 * 128 * 4);
  float* pmax = (float*)alloc((size_t)NB * 32 * 64 * 4);
  float* psum = (float*)alloc((size_t)NB * 32 * 64 * 4);
  unsigned long long* keyA = (unsigned long long*)alloc((size_t)65536 * 8);
  unsigned long long* keyB = (unsigned long long*)alloc((size_t)65536 * 8);
  float* pnbuf = (float*)alloc((size_t)64 * 4);
  if (off > ws_size) return;  // workspace too small — bail

  hipMemsetAsync(z, 0, 16 * 128 * 4, stream);
  k_pnorm<<<6, 64, 0, stream>>>(P[0], P[1], P[2], P[3], P[4], P[5], pnbuf);

  // build layer-0 CSR (dst-sorted src lists)
  hipMemsetAsync(cntA, 0, (size_t)65536 * 4, stream);
  k_count<<<NE / 256, 256, 0, stream>>>(edst0, cntA);
  k_scan_one<<<1, 1024, 0, stream>>>(cntA, offsA, cursor, 65536);
  k_fill0<<<NE / 256, 256, 0, stream>>>(esrc0, edst0, cursor, listA);

  const float* xcur = x0;
  int* ccnt = cntA;
  int* coffs = offsA;
  int* clist = listA;

  for (int i = 0; i < 6; ++i) {
    int n_per = N0 >> i;
    int ntot = NB * n_per;
    int k = n_per >> 1;

    if (i == 0) {
      k_sage_gather2<<<(ntot + 255) / 256, 256, 0, stream>>>(xcur, coffs, ccnt, clist, mean, ntot);
      k_sage0<<<(ntot + 15) / 16, 256, 0, stream>>>(xcur, mean, WL[0], BL[0], WR[0], P[0], pnbuf,
                                                    hA, score, ntot);
    } else if (i < 3) {
      k_sage_mm<<<ntot / 64, 256, 0, stream>>>(xcur, coffs, ccnt, clist, WL[i], BL[i], WR[i],
                                               P[i], pnbuf, i, hA, score);
    } else {
      int g = i - 3;
      k_gcn_mm<<<ntot / 64, 256, 0, stream>>>(xcur, WG[g], tmp);
      k_gcn_gather<<<(ntot + 3) / 4, 256, 0, stream>>>(tmp, coffs, ccnt, clist, BG[g], P[i],
                                                       pnbuf, i, hA, score, ntot);
    }

    // pool i: chunk sort (<=1024) + merge-path rounds
    int CH = (n_per < 1024) ? n_per : 1024;
    int single = (CH == n_per) ? 1 : 0;
    k_chunksort<<<ntot / CH, CH, (size_t)CH * 8, stream>>>(score, keyA, n_per, k, newidx, perm,
                                                           single);
    if (!single) {
      unsigned long long* cur = keyA;
      unsigned long long* nxt = keyB;
      for (int L = CH; L * 2 <= n_per; L <<= 1) {
        int fin = (L * 2 == n_per) ? 1 : 0;
        k_merge<<<(ntot + 255) / 256, 256, 0, stream>>>(cur, nxt, L, ntot, n_per, k, newidx, perm,
                                                        fin);
        unsigned long long* t2 = cur;
        cur = nxt;
        nxt = t2;
      }
    }

    int nch = k / 64;
    k_gather_ro<<<NB * nch, 1024, 0, stream>>>(hA, score, perm, hB, pmax, psum);

    if (i < 5) {
      int newn = NB * k;
      int* ncnt = (i & 1) ? cntA : cntB;
      int* noffs = (i & 1) ? offsA : offsB;
      int* nlist = (i & 1) ? listA : listB;
      k_newcount<<<(newn + 255) / 256, 256, 0, stream>>>(perm, coffs, ccnt, clist, newidx, ncnt,
                                                         newn);
      k_scan_one<<<1, 1024, 0, stream>>>(ncnt, noffs, nullptr, newn);
      k_newfill<<<(newn + 255) / 256, 256, 0, stream>>>(perm, coffs, ccnt, clist, newidx, noffs,
                                                        nlist, newn);
      ccnt = ncnt;
      coffs = noffs;
      clist = nlist;
    }

    k_readout_comb<<<NB, 64, 0, stream>>>(pmax, psum, z, k, nch);
    xcur = hB;
  }

  k_mlp<<<NB, 256, 0, stream>>>(z, lw1, lb1, lw2, lb2, lw3, lb3, (float*)d_out);
}

// Round 9
// 410.207 us; speedup vs baseline: 1.4284x; 1.4284x over previous
//
#include <hip/hip_runtime.h>
#include <math.h>

#define NB 16
#define N0 4096
#define NE 524288

// ---------------- CSR build (layer 0, atomic int cursor only) ----------------

static __global__ void k_count(const int* __restrict__ dst, int* __restrict__ cnt) {
  int e = blockIdx.x * 256 + threadIdx.x;
  if (e >= NE) return;
  atomicAdd(&cnt[dst[e]], 1);
}

static __global__ void k_fill0(const int* __restrict__ src, const int* __restrict__ dst,
                               int* __restrict__ cursor, int* __restrict__ list) {
  int e = blockIdx.x * 256 + threadIdx.x;
  if (e >= NE) return;
  int d = dst[e];
  int slot = atomicAdd(&cursor[d], 1);
  list[slot] = src[e];
}

// ---------------- exclusive scan (2-level, multi-block, n <= 65536) ----------------

static __global__ void k_scan1(const int* __restrict__ in, int* __restrict__ out,
                               int* __restrict__ bsum, int n) {
  __shared__ int ts[256];
  int base = blockIdx.x * 1024 + threadIdx.x * 4;
  int a0 = (base + 0 < n) ? in[base + 0] : 0;
  int a1 = (base + 1 < n) ? in[base + 1] : 0;
  int a2 = (base + 2 < n) ? in[base + 2] : 0;
  int a3 = (base + 3 < n) ? in[base + 3] : 0;
  int s = a0 + a1 + a2 + a3;
  ts[threadIdx.x] = s;
  __syncthreads();
  for (int off = 1; off < 256; off <<= 1) {
    int v = (threadIdx.x >= off) ? ts[threadIdx.x - off] : 0;
    __syncthreads();
    ts[threadIdx.x] += v;
    __syncthreads();
  }
  int excl = ts[threadIdx.x] - s;
  if (base + 0 < n) out[base + 0] = excl;
  excl += a0;
  if (base + 1 < n) out[base + 1] = excl;
  excl += a1;
  if (base + 2 < n) out[base + 2] = excl;
  excl += a2;
  if (base + 3 < n) out[base + 3] = excl;
  if (threadIdx.x == 255) bsum[blockIdx.x] = ts[255];
}

static __global__ void k_scan2(int* __restrict__ bsum, int nb) {
  __shared__ int t[64];
  int i = threadIdx.x;
  int v = (i < nb) ? bsum[i] : 0;
  t[i] = v;
  __syncthreads();
  for (int off = 1; off < 64; off <<= 1) {
    int u = (i >= off) ? t[i - off] : 0;
    __syncthreads();
    t[i] += u;
    __syncthreads();
  }
  if (i < nb) bsum[i] = t[i] - v;
}

// adds block offsets; optionally dual-writes a cursor copy
static __global__ void k_scan3(int* __restrict__ out, int* __restrict__ out2,
                               const int* __restrict__ bsum, int n) {
  int i = blockIdx.x * 256 + threadIdx.x;
  if (i < n) {
    int v = out[i] + bsum[i >> 10];
    out[i] = v;
    if (out2) out2[i] = v;
  }
}

// ---------------- CSR compaction after pooling (no atomics) ----------------

static __global__ void k_newcount(const int* __restrict__ perm, const int* __restrict__ offs,
                                  const int* __restrict__ cnt, const int* __restrict__ list,
                                  const int* __restrict__ newidx, int* __restrict__ ncnt,
                                  int newn) {
  int nn = blockIdx.x * 256 + threadIdx.x;
  if (nn >= newn) return;
  int old = perm[nn];
  int st = offs[old], c = cnt[old];
  int cc = 0;
  for (int j = 0; j < c; ++j) cc += (newidx[list[st + j]] >= 0);
  ncnt[nn] = cc;
}

static __global__ void k_newfill(const int* __restrict__ perm, const int* __restrict__ offs,
                                 const int* __restrict__ cnt, const int* __restrict__ list,
                                 const int* __restrict__ newidx, const int* __restrict__ noffs,
                                 int* __restrict__ nlist, int newn) {
  int nn = blockIdx.x * 256 + threadIdx.x;
  if (nn >= newn) return;
  int old = perm[nn];
  int st = offs[old], c = cnt[old];
  int pos = noffs[nn];
  for (int j = 0; j < c; ++j) {
    int s2 = newidx[list[st + j]];
    if (s2 >= 0) nlist[pos++] = s2;
  }
}

// ---------------- p-norms (all 6 layers, once) ----------------

static __global__ void k_pnorm(const float* __restrict__ p0, const float* __restrict__ p1,
                               const float* __restrict__ p2, const float* __restrict__ p3,
                               const float* __restrict__ p4, const float* __restrict__ p5,
                               float* __restrict__ pnbuf) {
  const float* pp = p0;
  switch (blockIdx.x) {
    case 1: pp = p1; break;
    case 2: pp = p2; break;
    case 3: pp = p3; break;
    case 4: pp = p4; break;
    case 5: pp = p5; break;
    default: break;
  }
  double v = (double)pp[threadIdx.x];
  v *= v;
#pragma unroll
  for (int off = 1; off < 64; off <<= 1) v += __shfl_xor(v, off);
  if (threadIdx.x == 0) pnbuf[blockIdx.x] = (float)(1.0 / sqrt(v));
}

// ---------------- SAGE ----------------

static __global__ void k_sage_gather2(const float* __restrict__ x, const int* __restrict__ offs,
                                      const int* __restrict__ cnt, const int* __restrict__ list,
                                      float* __restrict__ mean, int ntot) {
  int v = blockIdx.x * 256 + threadIdx.x;
  if (v >= ntot) return;
  int st = offs[v], c = cnt[v];
  float s0 = 0.f, s1 = 0.f;
  for (int j = 0; j < c; ++j) {
    int s = list[st + j];
    s0 += x[s * 2 + 0];
    s1 += x[s * 2 + 1];
  }
  float inv = 1.0f / fmaxf((float)c, 1.0f);
  mean[v * 2 + 0] = s0 * inv;
  mean[v * 2 + 1] = s1 * inv;
}

// layer-0 SAGE (DIN=2) + fused score (wave butterfly, double)
static __global__ void k_sage0(const float* __restrict__ x, const float* __restrict__ mean,
                               const float* __restrict__ wl, const float* __restrict__ blv,
                               const float* __restrict__ wr, const float* __restrict__ pvec,
                               const float* __restrict__ pnbuf, float* __restrict__ h,
                               float* __restrict__ score, int ntot) {
  __shared__ float wlT[2][65], wrT[2][65];
  if (threadIdx.x < 128) {
    int o = threadIdx.x >> 1, d = threadIdx.x & 1;
    wlT[d][o] = wl[o * 2 + d];
    wrT[d][o] = wr[o * 2 + d];
  }
  __syncthreads();
  int o = threadIdx.x & 63, vl = threadIdx.x >> 6;
  int base = blockIdx.x * 16 + vl * 4;
  float pn = pnbuf[0];
  float psl = pvec[o];
#pragma unroll
  for (int r = 0; r < 4; ++r) {
    int v = base + r;
    if (v >= ntot) break;
    float acc = blv[o] + mean[v * 2 + 0] * wlT[0][o] + mean[v * 2 + 1] * wlT[1][o] +
                x[v * 2 + 0] * wrT[0][o] + x[v * 2 + 1] * wrT[1][o];
    float hval = fmaxf(acc, 0.0f);
    h[(size_t)v * 64 + o] = hval;
    double sc = (double)hval * (double)psl;
#pragma unroll
    for (int off = 1; off < 64; off <<= 1) sc += __shfl_xor(sc, off);
    if (o == 0) score[v] = (float)sc * pn;
  }
}

// Fused SAGE DIN=64: in-kernel mean gather (16-node ILP) -> swizzled LDS A-tile,
// tiled GEMM 4x4/thread, bias+relu+score epilogue.
static __global__ __launch_bounds__(256) void k_sage_mm(
    const float* __restrict__ x, const int* __restrict__ offs, const int* __restrict__ cnt,
    const int* __restrict__ list, const float* __restrict__ wl, const float* __restrict__ blv,
    const float* __restrict__ wr, const float* __restrict__ pvec,
    const float* __restrict__ pnbuf, int pidx, float* __restrict__ h,
    float* __restrict__ score) {
  __shared__ float smem[16384];
  __shared__ float psh[64], bsh[64];
  float* xT = smem;
  float* mT = smem + 4096;
  float* wlT = smem + 8192;
  float* wrT = smem + 12288;
  int t = threadIdx.x;
  size_t nb = blockIdx.x;

  const float4* wl4 = (const float4*)wl;
  const float4* wr4 = (const float4*)wr;
  for (int i4 = t; i4 < 1024; i4 += 256) {
    int o = i4 >> 4, db = (i4 & 15) << 2;
    float4 L = wl4[i4], R = wr4[i4];
    float Lv[4] = {L.x, L.y, L.z, L.w}, Rv[4] = {R.x, R.y, R.z, R.w};
    int og = o >> 2, o3 = o & 3;
#pragma unroll
    for (int j = 0; j < 4; ++j) {
      int d = db + j;
      int col = ((og ^ (d & 15)) << 2) | o3;
      wlT[(d << 6) + col] = Lv[j];
      wrT[(d << 6) + col] = Rv[j];
    }
  }
  if (t < 64) {
    psh[t] = pvec[t];
    bsh[t] = blv[t];
  }
  const float4* x4 = (const float4*)(x + nb * 4096);
  for (int i = t; i < 1024; i += 256) {
    int node = i >> 4, db = (i & 15) << 2;
    float4 a = x4[i];
    float av[4] = {a.x, a.y, a.z, a.w};
    int ng = node >> 2, n0 = node & 3;
#pragma unroll
    for (int j = 0; j < 4; ++j) {
      int d = db + j;
      xT[(d << 6) + (((ng ^ (d & 15)) << 2) | n0)] = av[j];
    }
  }
  // mean gather: wave w handles nodes w*16..w*16+15 with 16-way load ILP
  {
    int lane = t & 63, w = t >> 6;
    int stq[16], cq[16];
    float accq[16];
    int cmax = 0;
#pragma unroll
    for (int q = 0; q < 16; ++q) {
      int gv = (int)nb * 64 + w * 16 + q;
      stq[q] = offs[gv];
      cq[q] = cnt[gv];
      accq[q] = 0.f;
      cmax = max(cmax, cq[q]);
    }
    for (int j = 0; j < cmax; ++j) {
#pragma unroll
      for (int q = 0; q < 16; ++q) {
        if (j < cq[q]) accq[q] += x[(size_t)list[stq[q] + j] * 64 + lane];
      }
    }
#pragma unroll
    for (int q = 0; q < 16; ++q) {
      int node = w * 16 + q;
      float mval = accq[q] * (1.0f / fmaxf((float)cq[q], 1.0f));
      int col = (((node >> 2) ^ (lane & 15)) << 2) | (node & 3);
      mT[(lane << 6) + col] = mval;
    }
  }
  __syncthreads();

  int tx = t & 15, ty = t >> 4;
  float acc[4][4] = {};
#pragma unroll 4
  for (int k = 0; k < 64; ++k) {
    int s = k & 15;
    int ca = (tx ^ s) << 2, cb = (ty ^ s) << 2;
    const float4 a = *(const float4*)&xT[(k << 6) + ca];
    const float4 m = *(const float4*)&mT[(k << 6) + ca];
    const float4 L = *(const float4*)&wlT[(k << 6) + cb];
    const float4 R = *(const float4*)&wrT[(k << 6) + cb];
    float A[4] = {a.x, a.y, a.z, a.w}, M[4] = {m.x, m.y, m.z, m.w};
    float Lv[4] = {L.x, L.y, L.z, L.w}, Rv[4] = {R.x, R.y, R.z, R.w};
#pragma unroll
    for (int r = 0; r < 4; ++r)
#pragma unroll
      for (int c = 0; c < 4; ++c) acc[r][c] += M[r] * Lv[c] + A[r] * Rv[c];
  }

  float pn = pnbuf[pidx];
  float hv[4][4];
  double sp[4];
#pragma unroll
  for (int r = 0; r < 4; ++r) {
    sp[r] = 0.0;
#pragma unroll
    for (int c = 0; c < 4; ++c) {
      float v = fmaxf(acc[r][c] + bsh[(ty << 2) + c], 0.0f);
      hv[r][c] = v;
      sp[r] += (double)v * (double)psh[(ty << 2) + c];
    }
  }
  __syncthreads();  // reuse smem
  float* hT = smem;                       // stride 68, swizzled col
  double* sred = (double*)(smem + 8192);  // [16][64]
#pragma unroll
  for (int r = 0; r < 4; ++r) {
    int node = (tx << 2) + r;
    int nk = node & 15;
#pragma unroll
    for (int c = 0; c < 4; ++c) hT[node * 68 + (((ty ^ nk) << 2) | c)] = hv[r][c];
    sred[(ty << 6) + node] = sp[r];
  }
  __syncthreads();
  float4* h4 = (float4*)(h + nb * 4096);
  for (int i = t; i < 1024; i += 256) {
    int node = i >> 4, q = i & 15;
    h4[i] = *(const float4*)&hT[node * 68 + ((q ^ (node & 15)) << 2)];
  }
  if (t < 64) {
    double ssum = 0.0;
    for (int g = 0; g < 16; ++g) ssum += sred[(g << 6) + t];
    score[nb * 64 + t] = (float)ssum * pn;
  }
}

// ---------------- GCN ----------------

static __global__ __launch_bounds__(256) void k_gcn_mm(const float* __restrict__ x,
                                                       const float* __restrict__ w,
                                                       float* __restrict__ h1) {
  __shared__ float smem[8192];
  float* xT = smem;
  float* wT = smem + 4096;
  int t = threadIdx.x;
  size_t nb = blockIdx.x;
  const float4* w4 = (const float4*)w;
  for (int i4 = t; i4 < 1024; i4 += 256) {
    int o = i4 >> 4, db = (i4 & 15) << 2;
    float4 W = w4[i4];
    float Wv[4] = {W.x, W.y, W.z, W.w};
    int og = o >> 2, o3 = o & 3;
#pragma unroll
    for (int j = 0; j < 4; ++j) {
      int d = db + j;
      wT[(d << 6) + (((og ^ (d & 15)) << 2) | o3)] = Wv[j];
    }
  }
  const float4* x4 = (const float4*)(x + nb * 4096);
  for (int i = t; i < 1024; i += 256) {
    int node = i >> 4, db = (i & 15) << 2;
    float4 a = x4[i];
    float av[4] = {a.x, a.y, a.z, a.w};
    int ng = node >> 2, n0 = node & 3;
#pragma unroll
    for (int j = 0; j < 4; ++j) {
      int d = db + j;
      xT[(d << 6) + (((ng ^ (d & 15)) << 2) | n0)] = av[j];
    }
  }
  __syncthreads();
  int tx = t & 15, ty = t >> 4;
  float acc[4][4] = {};
#pragma unroll 4
  for (int k = 0; k < 64; ++k) {
    int s = k & 15;
    const float4 a = *(const float4*)&xT[(k << 6) + ((tx ^ s) << 2)];
    const float4 W = *(const float4*)&wT[(k << 6) + ((ty ^ s) << 2)];
    float A[4] = {a.x, a.y, a.z, a.w}, Wv[4] = {W.x, W.y, W.z, W.w};
#pragma unroll
    for (int r = 0; r < 4; ++r)
#pragma unroll
      for (int c = 0; c < 4; ++c) acc[r][c] += A[r] * Wv[c];
  }
  __syncthreads();
  float* hT = smem;  // stride 68
#pragma unroll
  for (int r = 0; r < 4; ++r) {
    int node = (tx << 2) + r;
    int nk = node & 15;
#pragma unroll
    for (int c = 0; c < 4; ++c) hT[node * 68 + (((ty ^ nk) << 2) | c)] = acc[r][c];
  }
  __syncthreads();
  float4* h4 = (float4*)(h1 + nb * 4096);
  for (int i = t; i < 1024; i += 256) {
    int node = i >> 4, q = i & 15;
    h4[i] = *(const float4*)&hT[node * 68 + ((q ^ (node & 15)) << 2)];
  }
}

// fused: normalized gather + self term + bias + relu + score
static __global__ void k_gcn_gather(const float* __restrict__ h1, const int* __restrict__ offs,
                                    const int* __restrict__ cnt, const int* __restrict__ list,
                                    const float* __restrict__ b, const float* __restrict__ pvec,
                                    const float* __restrict__ pnbuf, int pidx,
                                    float* __restrict__ h, float* __restrict__ score, int ntot) {
  int lane = threadIdx.x & 63, vl = threadIdx.x >> 6;
  int v = blockIdx.x * 4 + vl;
  if (v >= ntot) return;
  int st = offs[v], c = cnt[v];
  float degv = 1.0f + (float)c;
  float ivd = 1.0f / sqrtf(degv);
  float acc = 0.f;
  for (int j = 0; j < c; ++j) {
    int s = list[st + j];
    float nrm = (1.0f / sqrtf(1.0f + (float)cnt[s])) * ivd;
    acc += h1[(size_t)s * 64 + lane] * nrm;
  }
  float outv = fmaxf(acc + h1[(size_t)v * 64 + lane] * (1.0f / degv) + b[lane], 0.0f);
  h[(size_t)v * 64 + lane] = outv;
  double sc = (double)outv * (double)pvec[lane];
#pragma unroll
  for (int off = 1; off < 64; off <<= 1) sc += __shfl_xor(sc, off);
  if (lane == 0) score[v] = (float)sc * pnbuf[pidx];
}

// ---------------- TopK pool: chunk bitonic (<=1024) + merge-path ----------------

static __global__ void k_chunksort(const float* __restrict__ score,
                                   unsigned long long* __restrict__ runs, int n_per, int k,
                                   int* __restrict__ newidx, int* __restrict__ perm, int single) {
  extern __shared__ unsigned long long sk[];
  int CH = blockDim.x;
  int g0 = blockIdx.x * CH;
  int b = g0 / n_per;
  int i = threadIdx.x;
  int gi = g0 + i;
  int li = gi - b * n_per;
  unsigned u = __float_as_uint(score[gi]);
  unsigned s = (u & 0x80000000u) ? u : ~(u | 0x80000000u);
  sk[i] = ((unsigned long long)s << 32) | (unsigned)li;
  __syncthreads();
  for (int ksz = 2; ksz <= CH; ksz <<= 1) {
    for (int j = ksz >> 1; j > 0; j >>= 1) {
      int ixj = i ^ j;
      if (ixj > i) {
        unsigned long long a = sk[i], c = sk[ixj];
        bool up = ((i & ksz) == 0);
        if ((a > c) == up) {
          sk[i] = c;
          sk[ixj] = a;
        }
      }
      __syncthreads();
    }
  }
  if (!single) {
    runs[gi] = sk[i];
  } else {
    int r = i;
    int idx = (int)(sk[r] & 0xFFFFFFFFu);
    int gidx = b * n_per + idx;
    if (r < k) {
      perm[b * k + r] = gidx;
      newidx[gidx] = b * k + r;
    } else {
      newidx[gidx] = -1;
    }
  }
}

static __global__ void k_merge(const unsigned long long* __restrict__ in,
                               unsigned long long* __restrict__ out, int L, int ntot, int n_per,
                               int k, int* __restrict__ newidx, int* __restrict__ perm,
                               int final) {
  int g = blockIdx.x * 256 + threadIdx.x;
  if (g >= ntot) return;
  unsigned long long key = in[g];
  int pair = g / (2 * L);
  int base = pair * 2 * L;
  int t = g - base;
  const unsigned long long* sib;
  int p;
  if (t < L) {
    sib = in + base + L;
    p = t;
  } else {
    sib = in + base;
    p = t - L;
  }
  int lo = 0, hi = L;
  while (lo < hi) {
    int mid = (lo + hi) >> 1;
    lo = (sib[mid] < key) ? mid + 1 : lo;
    hi = (sib[mid] < key) ? hi : mid;
  }
  int pos = p + lo;
  if (!final) {
    out[base + pos] = key;
  } else {
    int b = base / n_per;
    int idx = (int)(key & 0xFFFFFFFFu);
    int gidx = b * n_per + idx;
    if (pos < k) {
      perm[b * k + pos] = gidx;
      newidx[gidx] = b * k + pos;
    } else {
      newidx[gidx] = -1;
    }
  }
}

// ---------------- fused gather (tanh-scale) + readout partials ----------------
// block = 64 new nodes, 1024 threads; writes xnew + per-chunk max/sum partials.

static __global__ __launch_bounds__(1024) void k_gather_ro(
    const float* __restrict__ h, const float* __restrict__ score, const int* __restrict__ perm,
    float* __restrict__ xnew, float* __restrict__ pmax, float* __restrict__ psum) {
  __shared__ float tile[64 * 68];
  __shared__ float pm[16][65], ps[16][65];
  int t = threadIdx.x;
  int node = t >> 4, q = t & 15;
  int nn = blockIdx.x * 64 + node;
  int old = perm[nn];
  float tm = tanhf(score[old]);
  float4 v = *(const float4*)&h[(size_t)old * 64 + q * 4];
  v.x *= tm;
  v.y *= tm;
  v.z *= tm;
  v.w *= tm;
  *(float4*)&xnew[(size_t)nn * 64 + q * 4] = v;
  *(float4*)&tile[node * 68 + ((q ^ (node & 15)) << 2)] = v;
  __syncthreads();
  int slot = t >> 6, d = t & 63;
  int q2 = d >> 2, i3 = d & 3;
  float m = -INFINITY, s = 0.f;
#pragma unroll
  for (int r = 0; r < 4; ++r) {
    int nd = slot * 4 + r;
    float val = tile[nd * 68 + (((q2 ^ (nd & 15)) << 2) | i3)];
    m = fmaxf(m, val);
    s += val;
  }
  pm[slot][d] = m;
  ps[slot][d] = s;
  __syncthreads();
  if (t < 64) {
    float mm = -INFINITY, ss = 0.f;
#pragma unroll
    for (int sl = 0; sl < 16; ++sl) {
      mm = fmaxf(mm, pm[sl][t]);
      ss += ps[sl][t];
    }
    pmax[(size_t)blockIdx.x * 64 + t] = mm;
    psum[(size_t)blockIdx.x * 64 + t] = ss;
  }
}

static __global__ void k_readout_comb(const float* __restrict__ pmax,
                                      const float* __restrict__ psum, float* __restrict__ z,
                                      int k, int nch) {
  int b = blockIdx.x, d = threadIdx.x;
  float m = -INFINITY, s = 0.0f;
  for (int c = 0; c < nch; ++c) {
    m = fmaxf(m, pmax[((size_t)b * nch + c) * 64 + d]);
    s += psum[((size_t)b * nch + c) * 64 + d];
  }
  z[b * 128 + d] += m;
  z[b * 128 + 64 + d] += s / (float)k;
}

// ---------------- MLP + softmax ----------------

static __global__ void k_mlp(const float* __restrict__ z, const float* __restrict__ lw1,
                             const float* __restrict__ lb1, const float* __restrict__ lw2,
                             const float* __restrict__ lb2, const float* __restrict__ lw3,
                             const float* __restrict__ lb3, float* __restrict__ out) {
  __shared__ float zs[128], t1[128], t2[64], t3[256], red[256];
  int b = blockIdx.x, tid = threadIdx.x;
  if (tid < 128) zs[tid] = z[b * 128 + tid];
  __syncthreads();
  if (tid < 128) {
    double a = 0.0;
    for (int d = 0; d < 128; ++d) a += (double)lw1[tid * 128 + d] * (double)zs[d];
    t1[tid] = fmaxf((float)a + lb1[tid], 0.0f);
  }
  __syncthreads();
  if (tid < 64) {
    double a = 0.0;
    for (int d = 0; d < 128; ++d) a += (double)lw2[tid * 128 + d] * (double)t1[d];
    t2[tid] = fmaxf((float)a + lb2[tid], 0.0f);
  }
  __syncthreads();
  {
    double a = 0.0;
    for (int d = 0; d < 64; ++d) a += (double)lw3[tid * 64 + d] * (double)t2[d];
    t3[tid] = (float)a + lb3[tid];
  }
  __syncthreads();
  red[tid] = t3[tid];
  __syncthreads();
  for (int s = 128; s > 0; s >>= 1) {
    if (tid < s) red[tid] = fmaxf(red[tid], red[tid + s]);
    __syncthreads();
  }
  float mx = red[0];
  __syncthreads();
  float e = expf(t3[tid] - mx);
  red[tid] = e;
  __syncthreads();
  for (int s = 128; s > 0; s >>= 1) {
    if (tid < s) red[tid] += red[tid + s];
    __syncthreads();
  }
  out[b * 256 + tid] = e / red[0];
}

// ---------------- launch ----------------

extern "C" void kernel_launch(void* const* d_in, const int* in_sizes, int n_in,
                              void* d_out, int out_size, void* d_ws, size_t ws_size,
                              hipStream_t stream) {
  const float* x0 = (const float*)d_in[0];
  const int* esrc0 = (const int*)d_in[1];
  const int* edst0 = (const int*)d_in[2];
  const float* WL[3] = {(const float*)d_in[3], (const float*)d_in[6], (const float*)d_in[9]};
  const float* BL[3] = {(const float*)d_in[4], (const float*)d_in[7], (const float*)d_in[10]};
  const float* WR[3] = {(const float*)d_in[5], (const float*)d_in[8], (const float*)d_in[11]};
  const float* WG[3] = {(const float*)d_in[12], (const float*)d_in[14], (const float*)d_in[16]};
  const float* BG[3] = {(const float*)d_in[13], (const float*)d_in[15], (const float*)d_in[17]};
  const float* P[6] = {(const float*)d_in[18], (const float*)d_in[19], (const float*)d_in[20],
                       (const float*)d_in[21], (const float*)d_in[22], (const float*)d_in[23]};
  const float* lw1 = (const float*)d_in[24];
  const float* lb1 = (const float*)d_in[25];
  const float* lw2 = (const float*)d_in[26];
  const float* lb2 = (const float*)d_in[27];
  const float* lw3 = (const float*)d_in[28];
  const float* lb3 = (const float*)d_in[29];

  char* ws = (char*)d_ws;
  size_t off = 0;
  auto alloc = [&](size_t bytes) -> void* {
    void* p = ws + off;
    off += (bytes + 255) & ~(size_t)255;
    return p;
  };
  float* hA = (float*)alloc((size_t)65536 * 64 * 4);
  float* hB = (float*)alloc((size_t)32768 * 64 * 4);
  float* mean = (float*)alloc((size_t)65536 * 2 * 4);
  float* tmp = (float*)alloc((size_t)8192 * 64 * 4);
  float* score = (float*)alloc((size_t)65536 * 4);
  int* newidx = (int*)alloc((size_t)65536 * 4);
  int* perm = (int*)alloc((size_t)32768 * 4);
  int* cntA = (int*)alloc((size_t)65536 * 4);
  int* cntB = (int*)alloc((size_t)65536 * 4);
  int* offsA = (int*)alloc((size_t)65536 * 4);
  int* offsB = (int*)alloc((size_t)65536 * 4);
  int* cursor = (int*)alloc((size_t)65536 * 4);
  int* bsum = (int*)alloc((size_t)64 * 4);
  int* listA = (int*)alloc((size_t)NE * 4);
  int* listB = (int*)alloc((size_t)NE * 4);
  float* z = (float*)alloc((size_t)16 * 128 * 4);
  float* pmax = (float*)alloc((size_t)NB * 32 * 64 * 4);
  float* psum = (float*)alloc((size_t)NB * 32 * 64 * 4);
  unsigned long long* keyA = (unsigned long long*)alloc((size_t)65536 * 8);
  unsigned long long* keyB = (unsigned long long*)alloc((size_t)65536 * 8);
  float* pnbuf = (float*)alloc((size_t)64 * 4);
  if (off > ws_size) return;  // workspace too small — bail

  auto scan = [&](int* cntp, int* offsp, int* curp, int n) {
    int nblk = (n + 1023) / 1024;
    k_scan1<<<nblk, 256, 0, stream>>>(cntp, offsp, bsum, n);
    k_scan2<<<1, 64, 0, stream>>>(bsum, nblk);
    k_scan3<<<(n + 255) / 256, 256, 0, stream>>>(offsp, curp, bsum, n);
  };

  hipMemsetAsync(z, 0, 16 * 128 * 4, stream);
  k_pnorm<<<6, 64, 0, stream>>>(P[0], P[1], P[2], P[3], P[4], P[5], pnbuf);

  // build layer-0 CSR (dst-sorted src lists)
  hipMemsetAsync(cntA, 0, (size_t)65536 * 4, stream);
  k_count<<<NE / 256, 256, 0, stream>>>(edst0, cntA);
  scan(cntA, offsA, cursor, 65536);
  k_fill0<<<NE / 256, 256, 0, stream>>>(esrc0, edst0, cursor, listA);

  const float* xcur = x0;
  int* ccnt = cntA;
  int* coffs = offsA;
  int* clist = listA;

  for (int i = 0; i < 6; ++i) {
    int n_per = N0 >> i;
    int ntot = NB * n_per;
    int k = n_per >> 1;

    if (i == 0) {
      k_sage_gather2<<<(ntot + 255) / 256, 256, 0, stream>>>(xcur, coffs, ccnt, clist, mean, ntot);
      k_sage0<<<(ntot + 15) / 16, 256, 0, stream>>>(xcur, mean, WL[0], BL[0], WR[0], P[0], pnbuf,
                                                    hA, score, ntot);
    } else if (i < 3) {
      k_sage_mm<<<ntot / 64, 256, 0, stream>>>(xcur, coffs, ccnt, clist, WL[i], BL[i], WR[i],
                                               P[i], pnbuf, i, hA, score);
    } else {
      int g = i - 3;
      k_gcn_mm<<<ntot / 64, 256, 0, stream>>>(xcur, WG[g], tmp);
      k_gcn_gather<<<(ntot + 3) / 4, 256, 0, stream>>>(tmp, coffs, ccnt, clist, BG[g], P[i],
                                                       pnbuf, i, hA, score, ntot);
    }

    // pool i: chunk sort (<=1024) + merge-path rounds
    int CH = (n_per < 1024) ? n_per : 1024;
    int single = (CH == n_per) ? 1 : 0;
    k_chunksort<<<ntot / CH, CH, (size_t)CH * 8, stream>>>(score, keyA, n_per, k, newidx, perm,
                                                           single);
    if (!single) {
      unsigned long long* cur = keyA;
      unsigned long long* nxt = keyB;
      for (int L = CH; L * 2 <= n_per; L <<= 1) {
        int fin = (L * 2 == n_per) ? 1 : 0;
        k_merge<<<(ntot + 255) / 256, 256, 0, stream>>>(cur, nxt, L, ntot, n_per, k, newidx, perm,
                                                        fin);
        unsigned long long* t2 = cur;
        cur = nxt;
        nxt = t2;
      }
    }

    int nch = k / 64;
    k_gather_ro<<<NB * nch, 1024, 0, stream>>>(hA, score, perm, hB, pmax, psum);

    if (i < 5) {
      int newn = NB * k;
      int* ncnt = (i & 1) ? cntA : cntB;
      int* noffs = (i & 1) ? offsA : offsB;
      int* nlist = (i & 1) ? listA : listB;
      k_newcount<<<(newn + 255) / 256, 256, 0, stream>>>(perm, coffs, ccnt, clist, newidx, ncnt,
                                                         newn);
      scan(ncnt, noffs, nullptr, newn);
      k_newfill<<<(newn + 255) / 256, 256, 0, stream>>>(perm, coffs, ccnt, clist, newidx, noffs,
                                                        nlist, newn);
      ccnt = ncnt;
      coffs = noffs;
      clist = nlist;
    }

    k_readout_comb<<<NB, 64, 0, stream>>>(pmax, psum, z, k, nch);
    xcur = hB;
  }

  k_mlp<<<NB, 256, 0, stream>>>(z, lw1, lb1, lw2, lb2, lw3, lb3, (float*)d_out);
}

// Round 10
// 407.435 us; speedup vs baseline: 1.4381x; 1.0068x over previous
//
#include <hip/hip_runtime.h>
#include <math.h>

#define NB 16
#define N0 4096
#define NE 524288
#define CAPE 1280

// ---------------- CSR build (layer 0, atomic int cursor only) ----------------

static __global__ void k_count(const int* __restrict__ dst, int* __restrict__ cnt) {
  int e = blockIdx.x * 256 + threadIdx.x;
  if (e >= NE) return;
  atomicAdd(&cnt[dst[e]], 1);
}

static __global__ void k_fill0(const int* __restrict__ src, const int* __restrict__ dst,
                               int* __restrict__ cursor, int* __restrict__ list) {
  int e = blockIdx.x * 256 + threadIdx.x;
  if (e >= NE) return;
  int d = dst[e];
  int slot = atomicAdd(&cursor[d], 1);
  list[slot] = src[e];
}

// ---------------- exclusive scan (2-level, multi-block, n <= 65536) ----------------

static __global__ void k_scan1(const int* __restrict__ in, int* __restrict__ out,
                               int* __restrict__ bsum, int n) {
  __shared__ int ts[256];
  int base = blockIdx.x * 1024 + threadIdx.x * 4;
  int a0 = (base + 0 < n) ? in[base + 0] : 0;
  int a1 = (base + 1 < n) ? in[base + 1] : 0;
  int a2 = (base + 2 < n) ? in[base + 2] : 0;
  int a3 = (base + 3 < n) ? in[base + 3] : 0;
  int s = a0 + a1 + a2 + a3;
  ts[threadIdx.x] = s;
  __syncthreads();
  for (int off = 1; off < 256; off <<= 1) {
    int v = (threadIdx.x >= off) ? ts[threadIdx.x - off] : 0;
    __syncthreads();
    ts[threadIdx.x] += v;
    __syncthreads();
  }
  int excl = ts[threadIdx.x] - s;
  if (base + 0 < n) out[base + 0] = excl;
  excl += a0;
  if (base + 1 < n) out[base + 1] = excl;
  excl += a1;
  if (base + 2 < n) out[base + 2] = excl;
  excl += a2;
  if (base + 3 < n) out[base + 3] = excl;
  if (threadIdx.x == 255) bsum[blockIdx.x] = ts[255];
}

static __global__ void k_scan2(int* __restrict__ bsum, int nb) {
  __shared__ int t[64];
  int i = threadIdx.x;
  int v = (i < nb) ? bsum[i] : 0;
  t[i] = v;
  __syncthreads();
  for (int off = 1; off < 64; off <<= 1) {
    int u = (i >= off) ? t[i - off] : 0;
    __syncthreads();
    t[i] += u;
    __syncthreads();
  }
  if (i < nb) bsum[i] = t[i] - v;
}

static __global__ void k_scan3(int* __restrict__ out, int* __restrict__ out2,
                               const int* __restrict__ bsum, int n) {
  int i = blockIdx.x * 256 + threadIdx.x;
  if (i < n) {
    int v = out[i] + bsum[i >> 10];
    out[i] = v;
    if (out2) out2[i] = v;
  }
}

// ---------------- CSR compaction after pooling (no atomics) ----------------

static __global__ void k_newcount(const int* __restrict__ perm, const int* __restrict__ offs,
                                  const int* __restrict__ cnt, const int* __restrict__ list,
                                  const int* __restrict__ newidx, int* __restrict__ ncnt,
                                  int newn) {
  int nn = blockIdx.x * 256 + threadIdx.x;
  if (nn >= newn) return;
  int old = perm[nn];
  int st = offs[old], c = cnt[old];
  int cc = 0;
  for (int j = 0; j < c; ++j) cc += (newidx[list[st + j]] >= 0);
  ncnt[nn] = cc;
}

static __global__ void k_newfill(const int* __restrict__ perm, const int* __restrict__ offs,
                                 const int* __restrict__ cnt, const int* __restrict__ list,
                                 const int* __restrict__ newidx, const int* __restrict__ noffs,
                                 int* __restrict__ nlist, int newn) {
  int nn = blockIdx.x * 256 + threadIdx.x;
  if (nn >= newn) return;
  int old = perm[nn];
  int st = offs[old], c = cnt[old];
  int pos = noffs[nn];
  for (int j = 0; j < c; ++j) {
    int s2 = newidx[list[st + j]];
    if (s2 >= 0) nlist[pos++] = s2;
  }
}

// ---------------- p-norms (all 6 layers, once) ----------------

static __global__ void k_pnorm(const float* __restrict__ p0, const float* __restrict__ p1,
                               const float* __restrict__ p2, const float* __restrict__ p3,
                               const float* __restrict__ p4, const float* __restrict__ p5,
                               float* __restrict__ pnbuf) {
  const float* pp = p0;
  switch (blockIdx.x) {
    case 1: pp = p1; break;
    case 2: pp = p2; break;
    case 3: pp = p3; break;
    case 4: pp = p4; break;
    case 5: pp = p5; break;
    default: break;
  }
  double v = (double)pp[threadIdx.x];
  v *= v;
#pragma unroll
  for (int off = 1; off < 64; off <<= 1) v += __shfl_xor(v, off);
  if (threadIdx.x == 0) pnbuf[blockIdx.x] = (float)(1.0 / sqrt(v));
}

// ---------------- weight prep: transpose + swizzle into workspace (once) ----------------
// dst[(d<<6) + (((o>>2 ^ (d&15))<<2) | (o&3))] = w[o*64+d]
static __global__ void k_wprep(const float* __restrict__ w0, const float* __restrict__ w1,
                               const float* __restrict__ w2, const float* __restrict__ w3,
                               const float* __restrict__ w4, const float* __restrict__ w5,
                               const float* __restrict__ w6, float* __restrict__ wp) {
  const float* src = w0;
  switch (blockIdx.x) {
    case 1: src = w1; break;
    case 2: src = w2; break;
    case 3: src = w3; break;
    case 4: src = w4; break;
    case 5: src = w5; break;
    case 6: src = w6; break;
    default: break;
  }
  float* dst = wp + (size_t)blockIdx.x * 4096;
  const float4* w4p = (const float4*)src;
  for (int i4 = threadIdx.x; i4 < 1024; i4 += 256) {
    int o = i4 >> 4, db = (i4 & 15) << 2;
    float4 W = w4p[i4];
    float Wv[4] = {W.x, W.y, W.z, W.w};
    int og = o >> 2, o3 = o & 3;
#pragma unroll
    for (int j = 0; j < 4; ++j) {
      int d = db + j;
      dst[(d << 6) + (((og ^ (d & 15)) << 2) | o3)] = Wv[j];
    }
  }
}

// ---------------- SAGE ----------------

static __global__ void k_sage_gather2(const float* __restrict__ x, const int* __restrict__ offs,
                                      const int* __restrict__ cnt, const int* __restrict__ list,
                                      float* __restrict__ mean, int ntot) {
  int v = blockIdx.x * 256 + threadIdx.x;
  if (v >= ntot) return;
  int st = offs[v], c = cnt[v];
  float s0 = 0.f, s1 = 0.f;
  for (int j = 0; j < c; ++j) {
    int s = list[st + j];
    s0 += x[s * 2 + 0];
    s1 += x[s * 2 + 1];
  }
  float inv = 1.0f / fmaxf((float)c, 1.0f);
  mean[v * 2 + 0] = s0 * inv;
  mean[v * 2 + 1] = s1 * inv;
}

// layer-0 SAGE (DIN=2) + fused score (wave butterfly, double)
static __global__ void k_sage0(const float* __restrict__ x, const float* __restrict__ mean,
                               const float* __restrict__ wl, const float* __restrict__ blv,
                               const float* __restrict__ wr, const float* __restrict__ pvec,
                               const float* __restrict__ pnbuf, float* __restrict__ h,
                               float* __restrict__ score, int ntot) {
  __shared__ float wlT[2][65], wrT[2][65];
  if (threadIdx.x < 128) {
    int o = threadIdx.x >> 1, d = threadIdx.x & 1;
    wlT[d][o] = wl[o * 2 + d];
    wrT[d][o] = wr[o * 2 + d];
  }
  __syncthreads();
  int o = threadIdx.x & 63, vl = threadIdx.x >> 6;
  int base = blockIdx.x * 16 + vl * 4;
  float pn = pnbuf[0];
  float psl = pvec[o];
#pragma unroll
  for (int r = 0; r < 4; ++r) {
    int v = base + r;
    if (v >= ntot) break;
    float acc = blv[o] + mean[v * 2 + 0] * wlT[0][o] + mean[v * 2 + 1] * wlT[1][o] +
                x[v * 2 + 0] * wrT[0][o] + x[v * 2 + 1] * wrT[1][o];
    float hval = fmaxf(acc, 0.0f);
    h[(size_t)v * 64 + o] = hval;
    double sc = (double)hval * (double)psl;
#pragma unroll
    for (int off = 1; off < 64; off <<= 1) sc += __shfl_xor(sc, off);
    if (o == 0) score[v] = (float)sc * pn;
  }
}

// Fused SAGE DIN=64: LDS list-slice staging + mean gather -> swizzled LDS A-tile,
// tiled GEMM (weights from L1-resident prepped global), bias+relu+score epilogue.
static __global__ __launch_bounds__(256) void k_sage_mm(
    const float* __restrict__ x, const int* __restrict__ offs, const int* __restrict__ cnt,
    const int* __restrict__ list, const float* __restrict__ wlT, const float* __restrict__ blv,
    const float* __restrict__ wrT, const float* __restrict__ pvec,
    const float* __restrict__ pnbuf, int pidx, float* __restrict__ h,
    float* __restrict__ score) {
  __shared__ float smem[8192];
  __shared__ float psh[64], bsh[64];
  __shared__ int lds_list[CAPE];
  float* xT = smem;
  float* mT = smem + 4096;
  int t = threadIdx.x;
  size_t nb = blockIdx.x;

  if (t < 64) {
    psh[t] = pvec[t];
    bsh[t] = blv[t];
  }
  const float4* x4 = (const float4*)(x + nb * 4096);
  for (int i = t; i < 1024; i += 256) {
    int node = i >> 4, db = (i & 15) << 2;
    float4 a = x4[i];
    float av[4] = {a.x, a.y, a.z, a.w};
    int ng = node >> 2, n0 = node & 3;
#pragma unroll
    for (int j = 0; j < 4; ++j) {
      int d = db + j;
      xT[(d << 6) + (((ng ^ (d & 15)) << 2) | n0)] = av[j];
    }
  }
  // stage the block's contiguous edge-list slice
  int gv0 = (int)nb * 64;
  int st0 = offs[gv0];
  int nedge = offs[gv0 + 63] + cnt[gv0 + 63] - st0;
  int ncap = (nedge < CAPE) ? nedge : CAPE;
  for (int e = t; e < ncap; e += 256) lds_list[e] = list[st0 + e];
  __syncthreads();

  // mean gather: wave w handles nodes w*16..w*16+15 with 16-way load ILP
  {
    int lane = t & 63, w = t >> 6;
    int stq[16], cq[16];
    float accq[16];
    int cmax = 0;
#pragma unroll
    for (int q = 0; q < 16; ++q) {
      int gv = gv0 + w * 16 + q;
      stq[q] = offs[gv] - st0;
      cq[q] = cnt[gv];
      accq[q] = 0.f;
      cmax = max(cmax, cq[q]);
    }
    for (int j = 0; j < cmax; ++j) {
#pragma unroll
      for (int q = 0; q < 16; ++q) {
        if (j < cq[q]) {
          int idx = stq[q] + j;
          int sn = (idx < ncap) ? lds_list[idx] : list[st0 + idx];
          accq[q] += x[(size_t)sn * 64 + lane];
        }
      }
    }
#pragma unroll
    for (int q = 0; q < 16; ++q) {
      int node = w * 16 + q;
      float mval = accq[q] * (1.0f / fmaxf((float)cq[q], 1.0f));
      int col = (((node >> 2) ^ (lane & 15)) << 2) | (node & 3);
      mT[(lane << 6) + col] = mval;
    }
  }
  __syncthreads();

  int tx = t & 15, ty = t >> 4;
  float acc[4][4] = {};
#pragma unroll 4
  for (int k = 0; k < 64; ++k) {
    int s = k & 15;
    int ca = (tx ^ s) << 2, cb = (ty ^ s) << 2;
    const float4 a = *(const float4*)&xT[(k << 6) + ca];
    const float4 m = *(const float4*)&mT[(k << 6) + ca];
    const float4 L = *(const float4*)&wlT[(k << 6) + cb];
    const float4 R = *(const float4*)&wrT[(k << 6) + cb];
    float A[4] = {a.x, a.y, a.z, a.w}, M[4] = {m.x, m.y, m.z, m.w};
    float Lv[4] = {L.x, L.y, L.z, L.w}, Rv[4] = {R.x, R.y, R.z, R.w};
#pragma unroll
    for (int r = 0; r < 4; ++r)
#pragma unroll
      for (int c = 0; c < 4; ++c) acc[r][c] += M[r] * Lv[c] + A[r] * Rv[c];
  }

  float pn = pnbuf[pidx];
  float hv[4][4];
  double sp[4];
#pragma unroll
  for (int r = 0; r < 4; ++r) {
    sp[r] = 0.0;
#pragma unroll
    for (int c = 0; c < 4; ++c) {
      float v = fmaxf(acc[r][c] + bsh[(ty << 2) + c], 0.0f);
      hv[r][c] = v;
      sp[r] += (double)v * (double)psh[(ty << 2) + c];
    }
  }
  __syncthreads();  // reuse smem
  float* hT = smem;                       // 64*68 = 4352 floats, swizzled col
  double* sred = (double*)(smem + 4608);  // [16][64] doubles = 2048 floats
#pragma unroll
  for (int r = 0; r < 4; ++r) {
    int node = (tx << 2) + r;
    int nk = node & 15;
#pragma unroll
    for (int c = 0; c < 4; ++c) hT[node * 68 + (((ty ^ nk) << 2) | c)] = hv[r][c];
    sred[(ty << 6) + node] = sp[r];
  }
  __syncthreads();
  float4* h4 = (float4*)(h + nb * 4096);
  for (int i = t; i < 1024; i += 256) {
    int node = i >> 4, q = i & 15;
    h4[i] = *(const float4*)&hT[node * 68 + ((q ^ (node & 15)) << 2)];
  }
  if (t < 64) {
    double ssum = 0.0;
    for (int g = 0; g < 16; ++g) ssum += sred[(g << 6) + t];
    score[nb * 64 + t] = (float)ssum * pn;
  }
}

// ---------------- GCN ----------------

static __global__ __launch_bounds__(256) void k_gcn_mm(const float* __restrict__ x,
                                                       const float* __restrict__ wT,
                                                       float* __restrict__ h1) {
  __shared__ float smem[4608];
  float* xT = smem;
  int t = threadIdx.x;
  size_t nb = blockIdx.x;
  const float4* x4 = (const float4*)(x + nb * 4096);
  for (int i = t; i < 1024; i += 256) {
    int node = i >> 4, db = (i & 15) << 2;
    float4 a = x4[i];
    float av[4] = {a.x, a.y, a.z, a.w};
    int ng = node >> 2, n0 = node & 3;
#pragma unroll
    for (int j = 0; j < 4; ++j) {
      int d = db + j;
      xT[(d << 6) + (((ng ^ (d & 15)) << 2) | n0)] = av[j];
    }
  }
  __syncthreads();
  int tx = t & 15, ty = t >> 4;
  float acc[4][4] = {};
#pragma unroll 4
  for (int k = 0; k < 64; ++k) {
    int s = k & 15;
    const float4 a = *(const float4*)&xT[(k << 6) + ((tx ^ s) << 2)];
    const float4 W = *(const float4*)&wT[(k << 6) + ((ty ^ s) << 2)];
    float A[4] = {a.x, a.y, a.z, a.w}, Wv[4] = {W.x, W.y, W.z, W.w};
#pragma unroll
    for (int r = 0; r < 4; ++r)
#pragma unroll
      for (int c = 0; c < 4; ++c) acc[r][c] += A[r] * Wv[c];
  }
  __syncthreads();
  float* hT = smem;  // stride 68
#pragma unroll
  for (int r = 0; r < 4; ++r) {
    int node = (tx << 2) + r;
    int nk = node & 15;
#pragma unroll
    for (int c = 0; c < 4; ++c) hT[node * 68 + (((ty ^ nk) << 2) | c)] = acc[r][c];
  }
  __syncthreads();
  float4* h4 = (float4*)(h1 + nb * 4096);
  for (int i = t; i < 1024; i += 256) {
    int node = i >> 4, q = i & 15;
    h4[i] = *(const float4*)&hT[node * 68 + ((q ^ (node & 15)) << 2)];
  }
}

// fused: normalized gather + self term + bias + relu + score
static __global__ void k_gcn_gather(const float* __restrict__ h1, const int* __restrict__ offs,
                                    const int* __restrict__ cnt, const int* __restrict__ list,
                                    const float* __restrict__ b, const float* __restrict__ pvec,
                                    const float* __restrict__ pnbuf, int pidx,
                                    float* __restrict__ h, float* __restrict__ score, int ntot) {
  int lane = threadIdx.x & 63, vl = threadIdx.x >> 6;
  int v = blockIdx.x * 4 + vl;
  if (v >= ntot) return;
  int st = offs[v], c = cnt[v];
  float degv = 1.0f + (float)c;
  float ivd = 1.0f / sqrtf(degv);
  float acc = 0.f;
  for (int j = 0; j < c; ++j) {
    int s = list[st + j];
    float nrm = (1.0f / sqrtf(1.0f + (float)cnt[s])) * ivd;
    acc += h1[(size_t)s * 64 + lane] * nrm;
  }
  float outv = fmaxf(acc + h1[(size_t)v * 64 + lane] * (1.0f / degv) + b[lane], 0.0f);
  h[(size_t)v * 64 + lane] = outv;
  double sc = (double)outv * (double)pvec[lane];
#pragma unroll
  for (int off = 1; off < 64; off <<= 1) sc += __shfl_xor(sc, off);
  if (lane == 0) score[v] = (float)sc * pnbuf[pidx];
}

// ---------------- TopK pool: chunk bitonic (<=1024) + merge-path ----------------

static __global__ void k_chunksort(const float* __restrict__ score,
                                   unsigned long long* __restrict__ runs, int n_per, int k,
                                   int* __restrict__ newidx, int* __restrict__ perm, int single) {
  extern __shared__ unsigned long long sk[];
  int CH = blockDim.x;
  int g0 = blockIdx.x * CH;
  int b = g0 / n_per;
  int i = threadIdx.x;
  int gi = g0 + i;
  int li = gi - b * n_per;
  unsigned u = __float_as_uint(score[gi]);
  unsigned s = (u & 0x80000000u) ? u : ~(u | 0x80000000u);
  sk[i] = ((unsigned long long)s << 32) | (unsigned)li;
  __syncthreads();
  for (int ksz = 2; ksz <= CH; ksz <<= 1) {
    for (int j = ksz >> 1; j > 0; j >>= 1) {
      int ixj = i ^ j;
      if (ixj > i) {
        unsigned long long a = sk[i], c = sk[ixj];
        bool up = ((i & ksz) == 0);
        if ((a > c) == up) {
          sk[i] = c;
          sk[ixj] = a;
        }
      }
      __syncthreads();
    }
  }
  if (!single) {
    runs[gi] = sk[i];
  } else {
    int r = i;
    int idx = (int)(sk[r] & 0xFFFFFFFFu);
    int gidx = b * n_per + idx;
    if (r < k) {
      perm[b * k + r] = gidx;
      newidx[gidx] = b * k + r;
    } else {
      newidx[gidx] = -1;
    }
  }
}

static __global__ void k_merge(const unsigned long long* __restrict__ in,
                               unsigned long long* __restrict__ out, int L, int ntot, int n_per,
                               int k, int* __restrict__ newidx, int* __restrict__ perm,
                               int final) {
  int g = blockIdx.x * 256 + threadIdx.x;
  if (g >= ntot) return;
  unsigned long long key = in[g];
  int pair = g / (2 * L);
  int base = pair * 2 * L;
  int t = g - base;
  const unsigned long long* sib;
  int p;
  if (t < L) {
    sib = in + base + L;
    p = t;
  } else {
    sib = in + base;
    p = t - L;
  }
  int lo = 0, hi = L;
  while (lo < hi) {
    int mid = (lo + hi) >> 1;
    lo = (sib[mid] < key) ? mid + 1 : lo;
    hi = (sib[mid] < key) ? hi : mid;
  }
  int pos = p + lo;
  if (!final) {
    out[base + pos] = key;
  } else {
    int b = base / n_per;
    int idx = (int)(key & 0xFFFFFFFFu);
    int gidx = b * n_per + idx;
    if (pos < k) {
      perm[b * k + pos] = gidx;
      newidx[gidx] = b * k + pos;
    } else {
      newidx[gidx] = -1;
    }
  }
}

// ---------------- fused gather (tanh-scale) + readout partials ----------------

static __global__ __launch_bounds__(1024) void k_gather_ro(
    const float* __restrict__ h, const float* __restrict__ score, const int* __restrict__ perm,
    float* __restrict__ xnew, float* __restrict__ pmax, float* __restrict__ psum) {
  __shared__ float tile[64 * 68];
  __shared__ float pm[16][65], ps[16][65];
  int t = threadIdx.x;
  int node = t >> 4, q = t & 15;
  int nn = blockIdx.x * 64 + node;
  int old = perm[nn];
  float tm = tanhf(score[old]);
  float4 v = *(const float4*)&h[(size_t)old * 64 + q * 4];
  v.x *= tm;
  v.y *= tm;
  v.z *= tm;
  v.w *= tm;
  *(float4*)&xnew[(size_t)nn * 64 + q * 4] = v;
  *(float4*)&tile[node * 68 + ((q ^ (node & 15)) << 2)] = v;
  __syncthreads();
  int slot = t >> 6, d = t & 63;
  int q2 = d >> 2, i3 = d & 3;
  float m = -INFINITY, s = 0.f;
#pragma unroll
  for (int r = 0; r < 4; ++r) {
    int nd = slot * 4 + r;
    float val = tile[nd * 68 + (((q2 ^ (nd & 15)) << 2) | i3)];
    m = fmaxf(m, val);
    s += val;
  }
  pm[slot][d] = m;
  ps[slot][d] = s;
  __syncthreads();
  if (t < 64) {
    float mm = -INFINITY, ss = 0.f;
#pragma unroll
    for (int sl = 0; sl < 16; ++sl) {
      mm = fmaxf(mm, pm[sl][t]);
      ss += ps[sl][t];
    }
    pmax[(size_t)blockIdx.x * 64 + t] = mm;
    psum[(size_t)blockIdx.x * 64 + t] = ss;
  }
}

static __global__ void k_readout_comb(const float* __restrict__ pmax,
                                      const float* __restrict__ psum, float* __restrict__ z,
                                      int k, int nch) {
  int b = blockIdx.x, d = threadIdx.x;
  float m = -INFINITY, s = 0.0f;
  for (int c = 0; c < nch; ++c) {
    m = fmaxf(m, pmax[((size_t)b * nch + c) * 64 + d]);
    s += psum[((size_t)b * nch + c) * 64 + d];
  }
  z[b * 128 + d] += m;
  z[b * 128 + 64 + d] += s / (float)k;
}

// ---------------- MLP + softmax ----------------

static __global__ void k_mlp(const float* __restrict__ z, const float* __restrict__ lw1,
                             const float* __restrict__ lb1, const float* __restrict__ lw2,
                             const float* __restrict__ lb2, const float* __restrict__ lw3,
                             const float* __restrict__ lb3, float* __restrict__ out) {
  __shared__ float zs[128], t1[128], t2[64], t3[256], red[256];
  int b = blockIdx.x, tid = threadIdx.x;
  if (tid < 128) zs[tid] = z[b * 128 + tid];
  __syncthreads();
  if (tid < 128) {
    double a = 0.0;
    for (int d = 0; d < 128; ++d) a += (double)lw1[tid * 128 + d] * (double)zs[d];
    t1[tid] = fmaxf((float)a + lb1[tid], 0.0f);
  }
  __syncthreads();
  if (tid < 64) {
    double a = 0.0;
    for (int d = 0; d < 128; ++d) a += (double)lw2[tid * 128 + d] * (double)t1[d];
    t2[tid] = fmaxf((float)a + lb2[tid], 0.0f);
  }
  __syncthreads();
  {
    double a = 0.0;
    for (int d = 0; d < 64; ++d) a += (double)lw3[tid * 64 + d] * (double)t2[d];
    t3[tid] = (float)a + lb3[tid];
  }
  __syncthreads();
  red[tid] = t3[tid];
  __syncthreads();
  for (int s = 128; s > 0; s >>= 1) {
    if (tid < s) red[tid] = fmaxf(red[tid], red[tid + s]);
    __syncthreads();
  }
  float mx = red[0];
  __syncthreads();
  float e = expf(t3[tid] - mx);
  red[tid] = e;
  __syncthreads();
  for (int s = 128; s > 0; s >>= 1) {
    if (tid < s) red[tid] += red[tid + s];
    __syncthreads();
  }
  out[b * 256 + tid] = e / red[0];
}

// ---------------- launch ----------------

extern "C" void kernel_launch(void* const* d_in, const int* in_sizes, int n_in,
                              void* d_out, int out_size, void* d_ws, size_t ws_size,
                              hipStream_t stream) {
  const float* x0 = (const float*)d_in[0];
  const int* esrc0 = (const int*)d_in[1];
  const int* edst0 = (const int*)d_in[2];
  const float* WL[3] = {(const float*)d_in[3], (const float*)d_in[6], (const float*)d_in[9]};
  const float* BL[3] = {(const float*)d_in[4], (const float*)d_in[7], (const float*)d_in[10]};
  const float* WR[3] = {(const float*)d_in[5], (const float*)d_in[8], (const float*)d_in[11]};
  const float* WG[3] = {(const float*)d_in[12], (const float*)d_in[14], (const float*)d_in[16]};
  const float* BG[3] = {(const float*)d_in[13], (const float*)d_in[15], (const float*)d_in[17]};
  const float* P[6] = {(const float*)d_in[18], (const float*)d_in[19], (const float*)d_in[20],
                       (const float*)d_in[21], (const float*)d_in[22], (const float*)d_in[23]};
  const float* lw1 = (const float*)d_in[24];
  const float* lb1 = (const float*)d_in[25];
  const float* lw2 = (const float*)d_in[26];
  const float* lb2 = (const float*)d_in[27];
  const float* lw3 = (const float*)d_in[28];
  const float* lb3 = (const float*)d_in[29];

  char* ws = (char*)d_ws;
  size_t off = 0;
  auto alloc = [&](size_t bytes) -> void* {
    void* p = ws + off;
    off += (bytes + 255) & ~(size_t)255;
    return p;
  };
  float* hA = (float*)alloc((size_t)65536 * 64 * 4);
  float* hB = (float*)alloc((size_t)32768 * 64 * 4);
  float* mean = (float*)alloc((size_t)65536 * 2 * 4);
  float* tmp = (float*)alloc((size_t)8192 * 64 * 4);
  float* score = (float*)alloc((size_t)65536 * 4);
  int* newidx = (int*)alloc((size_t)65536 * 4);
  int* perm = (int*)alloc((size_t)32768 * 4);
  int* cntA = (int*)alloc((size_t)65536 * 4);
  int* cntB = (int*)alloc((size_t)65536 * 4);
  int* offsA = (int*)alloc((size_t)65536 * 4);
  int* offsB = (int*)alloc((size_t)65536 * 4);
  int* cursor = (int*)alloc((size_t)65536 * 4);
  int* bsum = (int*)alloc((size_t)64 * 4);
  int* listA = (int*)alloc((size_t)NE * 4);
  int* listB = (int*)alloc((size_t)NE * 4);
  float* z = (float*)alloc((size_t)16 * 128 * 4);
  float* pmax = (float*)alloc((size_t)NB * 32 * 64 * 4);
  float* psum = (float*)alloc((size_t)NB * 32 * 64 * 4);
  unsigned long long* keyA = (unsigned long long*)alloc((size_t)65536 * 8);
  unsigned long long* keyB = (unsigned long long*)alloc((size_t)65536 * 8);
  float* pnbuf = (float*)alloc((size_t)64 * 4);
  float* wp = (float*)alloc((size_t)7 * 4096 * 4);
  if (off > ws_size) return;  // workspace too small — bail

  auto scan = [&](int* cntp, int* offsp, int* curp, int n) {
    int nblk = (n + 1023) / 1024;
    k_scan1<<<nblk, 256, 0, stream>>>(cntp, offsp, bsum, n);
    k_scan2<<<1, 64, 0, stream>>>(bsum, nblk);
    k_scan3<<<(n + 255) / 256, 256, 0, stream>>>(offsp, curp, bsum, n);
  };

  hipMemsetAsync(z, 0, 16 * 128 * 4, stream);
  k_pnorm<<<6, 64, 0, stream>>>(P[0], P[1], P[2], P[3], P[4], P[5], pnbuf);
  k_wprep<<<7, 256, 0, stream>>>(WL[1], WR[1], WL[2], WR[2], WG[0], WG[1], WG[2], wp);

  // build layer-0 CSR (dst-sorted src lists)
  hipMemsetAsync(cntA, 0, (size_t)65536 * 4, stream);
  k_count<<<NE / 256, 256, 0, stream>>>(edst0, cntA);
  scan(cntA, offsA, cursor, 65536);
  k_fill0<<<NE / 256, 256, 0, stream>>>(esrc0, edst0, cursor, listA);

  const float* xcur = x0;
  int* ccnt = cntA;
  int* coffs = offsA;
  int* clist = listA;

  for (int i = 0; i < 6; ++i) {
    int n_per = N0 >> i;
    int ntot = NB * n_per;
    int k = n_per >> 1;

    if (i == 0) {
      k_sage_gather2<<<(ntot + 255) / 256, 256, 0, stream>>>(xcur, coffs, ccnt, clist, mean, ntot);
      k_sage0<<<(ntot + 15) / 16, 256, 0, stream>>>(xcur, mean, WL[0], BL[0], WR[0], P[0], pnbuf,
                                                    hA, score, ntot);
    } else if (i < 3) {
      const float* wlp = wp + (size_t)((i - 1) * 2 + 0) * 4096;
      const float* wrp = wp + (size_t)((i - 1) * 2 + 1) * 4096;
      k_sage_mm<<<ntot / 64, 256, 0, stream>>>(xcur, coffs, ccnt, clist, wlp, BL[i], wrp, P[i],
                                               pnbuf, i, hA, score);
    } else {
      int g = i - 3;
      k_gcn_mm<<<ntot / 64, 256, 0, stream>>>(xcur, wp + (size_t)(4 + g) * 4096, tmp);
      k_gcn_gather<<<(ntot + 3) / 4, 256, 0, stream>>>(tmp, coffs, ccnt, clist, BG[g], P[i],
                                                       pnbuf, i, hA, score, ntot);
    }

    // pool i: chunk sort (<=1024) + merge-path rounds
    int CH = (n_per < 1024) ? n_per : 1024;
    int single = (CH == n_per) ? 1 : 0;
    k_chunksort<<<ntot / CH, CH, (size_t)CH * 8, stream>>>(score, keyA, n_per, k, newidx, perm,
                                                           single);
    if (!single) {
      unsigned long long* cur = keyA;
      unsigned long long* nxt = keyB;
      for (int L = CH; L * 2 <= n_per; L <<= 1) {
        int fin = (L * 2 == n_per) ? 1 : 0;
        k_merge<<<(ntot + 255) / 256, 256, 0, stream>>>(cur, nxt, L, ntot, n_per, k, newidx, perm,
                                                        fin);
        unsigned long long* t2 = cur;
        cur = nxt;
        nxt = t2;
      }
    }

    int nch = k / 64;
    k_gather_ro<<<NB * nch, 1024, 0, stream>>>(hA, score, perm, hB, pmax, psum);

    if (i < 5) {
      int newn = NB * k;
      int* ncnt = (i & 1) ? cntA : cntB;
      int* noffs = (i & 1) ? offsA : offsB;
      int* nlist = (i & 1) ? listA : listB;
      k_newcount<<<(newn + 255) / 256, 256, 0, stream>>>(perm, coffs, ccnt, clist, newidx, ncnt,
                                                         newn);
      scan(ncnt, noffs, nullptr, newn);
      k_newfill<<<(newn + 255) / 256, 256, 0, stream>>>(perm, coffs, ccnt, clist, newidx, noffs,
                                                        nlist, newn);
      ccnt = ncnt;
      coffs = noffs;
      clist = nlist;
    }

    k_readout_comb<<<NB, 64, 0, stream>>>(pmax, psum, z, k, nch);
    xcur = hB;
  }

  k_mlp<<<NB, 256, 0, stream>>>(z, lw1, lb1, lw2, lb2, lw3, lb3, (float*)d_out);
}

// Round 11
// 401.377 us; speedup vs baseline: 1.4598x; 1.0151x over previous
//
#include <hip/hip_runtime.h>
#include <math.h>

#define NB 16
#define N0 4096
#define NE 524288
#define CAPE 1280

// ---------------- CSR build (layer 0, atomic int cursor only) ----------------

static __global__ void k_count(const int* __restrict__ dst, int* __restrict__ cnt) {
  int e = blockIdx.x * 256 + threadIdx.x;
  if (e >= NE) return;
  atomicAdd(&cnt[dst[e]], 1);
}

static __global__ void k_fill0(const int* __restrict__ src, const int* __restrict__ dst,
                               int* __restrict__ cursor, int* __restrict__ list) {
  int e = blockIdx.x * 256 + threadIdx.x;
  if (e >= NE) return;
  int d = dst[e];
  int slot = atomicAdd(&cursor[d], 1);
  list[slot] = src[e];
}

// ---------------- exclusive scan (2-level, multi-block, n <= 65536) ----------------

static __global__ void k_scan1(const int* __restrict__ in, int* __restrict__ out,
                               int* __restrict__ bsum, int n) {
  __shared__ int ts[256];
  int base = blockIdx.x * 1024 + threadIdx.x * 4;
  int a0 = (base + 0 < n) ? in[base + 0] : 0;
  int a1 = (base + 1 < n) ? in[base + 1] : 0;
  int a2 = (base + 2 < n) ? in[base + 2] : 0;
  int a3 = (base + 3 < n) ? in[base + 3] : 0;
  int s = a0 + a1 + a2 + a3;
  ts[threadIdx.x] = s;
  __syncthreads();
  for (int off = 1; off < 256; off <<= 1) {
    int v = (threadIdx.x >= off) ? ts[threadIdx.x - off] : 0;
    __syncthreads();
    ts[threadIdx.x] += v;
    __syncthreads();
  }
  int excl = ts[threadIdx.x] - s;
  if (base + 0 < n) out[base + 0] = excl;
  excl += a0;
  if (base + 1 < n) out[base + 1] = excl;
  excl += a1;
  if (base + 2 < n) out[base + 2] = excl;
  excl += a2;
  if (base + 3 < n) out[base + 3] = excl;
  if (threadIdx.x == 255) bsum[blockIdx.x] = ts[255];
}

static __global__ void k_scan2(int* __restrict__ bsum, int nb) {
  __shared__ int t[64];
  int i = threadIdx.x;
  int v = (i < nb) ? bsum[i] : 0;
  t[i] = v;
  __syncthreads();
  for (int off = 1; off < 64; off <<= 1) {
    int u = (i >= off) ? t[i - off] : 0;
    __syncthreads();
    t[i] += u;
    __syncthreads();
  }
  if (i < nb) bsum[i] = t[i] - v;
}

static __global__ void k_scan3(int* __restrict__ out, int* __restrict__ out2,
                               const int* __restrict__ bsum, int n) {
  int i = blockIdx.x * 256 + threadIdx.x;
  if (i < n) {
    int v = out[i] + bsum[i >> 10];
    out[i] = v;
    if (out2) out2[i] = v;
  }
}

// ---------------- CSR compaction after pooling (no atomics) ----------------

static __global__ void k_newcount(const int* __restrict__ perm, const int* __restrict__ offs,
                                  const int* __restrict__ cnt, const int* __restrict__ list,
                                  const int* __restrict__ newidx, int* __restrict__ ncnt,
                                  int newn) {
  int nn = blockIdx.x * 256 + threadIdx.x;
  if (nn >= newn) return;
  int old = perm[nn];
  int st = offs[old], c = cnt[old];
  int cc = 0;
  for (int j = 0; j < c; ++j) cc += (newidx[list[st + j]] >= 0);
  ncnt[nn] = cc;
}

static __global__ void k_newfill(const int* __restrict__ perm, const int* __restrict__ offs,
                                 const int* __restrict__ cnt, const int* __restrict__ list,
                                 const int* __restrict__ newidx, const int* __restrict__ noffs,
                                 int* __restrict__ nlist, int newn) {
  int nn = blockIdx.x * 256 + threadIdx.x;
  if (nn >= newn) return;
  int old = perm[nn];
  int st = offs[old], c = cnt[old];
  int pos = noffs[nn];
  for (int j = 0; j < c; ++j) {
    int s2 = newidx[list[st + j]];
    if (s2 >= 0) nlist[pos++] = s2;
  }
}

// ---------------- p-norms (all 6 layers, once) ----------------

static __global__ void k_pnorm(const float* __restrict__ p0, const float* __restrict__ p1,
                               const float* __restrict__ p2, const float* __restrict__ p3,
                               const float* __restrict__ p4, const float* __restrict__ p5,
                               float* __restrict__ pnbuf) {
  const float* pp = p0;
  switch (blockIdx.x) {
    case 1: pp = p1; break;
    case 2: pp = p2; break;
    case 3: pp = p3; break;
    case 4: pp = p4; break;
    case 5: pp = p5; break;
    default: break;
  }
  double v = (double)pp[threadIdx.x];
  v *= v;
#pragma unroll
  for (int off = 1; off < 64; off <<= 1) v += __shfl_xor(v, off);
  if (threadIdx.x == 0) pnbuf[blockIdx.x] = (float)(1.0 / sqrt(v));
}

// ---------------- weight prep: transpose + swizzle into workspace (once) ----------------

static __global__ void k_wprep(const float* __restrict__ w0, const float* __restrict__ w1,
                               const float* __restrict__ w2, const float* __restrict__ w3,
                               const float* __restrict__ w4, const float* __restrict__ w5,
                               const float* __restrict__ w6, float* __restrict__ wp) {
  const float* src = w0;
  switch (blockIdx.x) {
    case 1: src = w1; break;
    case 2: src = w2; break;
    case 3: src = w3; break;
    case 4: src = w4; break;
    case 5: src = w5; break;
    case 6: src = w6; break;
    default: break;
  }
  float* dst = wp + (size_t)blockIdx.x * 4096;
  const float4* w4p = (const float4*)src;
  for (int i4 = threadIdx.x; i4 < 1024; i4 += 256) {
    int o = i4 >> 4, db = (i4 & 15) << 2;
    float4 W = w4p[i4];
    float Wv[4] = {W.x, W.y, W.z, W.w};
    int og = o >> 2, o3 = o & 3;
#pragma unroll
    for (int j = 0; j < 4; ++j) {
      int d = db + j;
      dst[(d << 6) + (((og ^ (d & 15)) << 2) | o3)] = Wv[j];
    }
  }
}

// ---------------- SAGE ----------------

static __global__ void k_sage_gather2(const float* __restrict__ x, const int* __restrict__ offs,
                                      const int* __restrict__ cnt, const int* __restrict__ list,
                                      float* __restrict__ mean, int ntot) {
  int v = blockIdx.x * 256 + threadIdx.x;
  if (v >= ntot) return;
  int st = offs[v], c = cnt[v];
  float s0 = 0.f, s1 = 0.f;
  for (int j = 0; j < c; ++j) {
    int s = list[st + j];
    s0 += x[s * 2 + 0];
    s1 += x[s * 2 + 1];
  }
  float inv = 1.0f / fmaxf((float)c, 1.0f);
  mean[v * 2 + 0] = s0 * inv;
  mean[v * 2 + 1] = s1 * inv;
}

// layer-0 SAGE (DIN=2) + fused score (wave butterfly, double)
static __global__ void k_sage0(const float* __restrict__ x, const float* __restrict__ mean,
                               const float* __restrict__ wl, const float* __restrict__ blv,
                               const float* __restrict__ wr, const float* __restrict__ pvec,
                               const float* __restrict__ pnbuf, float* __restrict__ h,
                               float* __restrict__ score, int ntot) {
  __shared__ float wlT[2][65], wrT[2][65];
  if (threadIdx.x < 128) {
    int o = threadIdx.x >> 1, d = threadIdx.x & 1;
    wlT[d][o] = wl[o * 2 + d];
    wrT[d][o] = wr[o * 2 + d];
  }
  __syncthreads();
  int o = threadIdx.x & 63, vl = threadIdx.x >> 6;
  int base = blockIdx.x * 16 + vl * 4;
  float pn = pnbuf[0];
  float psl = pvec[o];
#pragma unroll
  for (int r = 0; r < 4; ++r) {
    int v = base + r;
    if (v >= ntot) break;
    float acc = blv[o] + mean[v * 2 + 0] * wlT[0][o] + mean[v * 2 + 1] * wlT[1][o] +
                x[v * 2 + 0] * wrT[0][o] + x[v * 2 + 1] * wrT[1][o];
    float hval = fmaxf(acc, 0.0f);
    h[(size_t)v * 64 + o] = hval;
    double sc = (double)hval * (double)psl;
#pragma unroll
    for (int off = 1; off < 64; off <<= 1) sc += __shfl_xor(sc, off);
    if (o == 0) score[v] = (float)sc * pn;
  }
}

// Fused SAGE DIN=64: XCD-swizzled blocks, LDS list staging, BRANCHLESS 16-way
// ILP mean gather -> swizzled LDS A-tile, tiled GEMM, bias+relu+score epilogue.
static __global__ __launch_bounds__(256) void k_sage_mm(
    const float* __restrict__ x, const int* __restrict__ offs, const int* __restrict__ cnt,
    const int* __restrict__ list, const float* __restrict__ wlT, const float* __restrict__ blv,
    const float* __restrict__ wrT, const float* __restrict__ pvec,
    const float* __restrict__ pnbuf, int pidx, float* __restrict__ h,
    float* __restrict__ score) {
  __shared__ float smem[8192];
  __shared__ float psh[64], bsh[64];
  __shared__ int lds_list[CAPE];
  float* xT = smem;
  float* mT = smem + 4096;
  int t = threadIdx.x;
  // bijective XCD swizzle: contiguous graph chunks per XCD (grid % 8 == 0)
  size_t nb = (size_t)((blockIdx.x & 7) * (gridDim.x >> 3) + (blockIdx.x >> 3));

  if (t < 64) {
    psh[t] = pvec[t];
    bsh[t] = blv[t];
  }
  const float4* x4 = (const float4*)(x + nb * 4096);
  for (int i = t; i < 1024; i += 256) {
    int node = i >> 4, db = (i & 15) << 2;
    float4 a = x4[i];
    float av[4] = {a.x, a.y, a.z, a.w};
    int ng = node >> 2, n0 = node & 3;
#pragma unroll
    for (int j = 0; j < 4; ++j) {
      int d = db + j;
      xT[(d << 6) + (((ng ^ (d & 15)) << 2) | n0)] = av[j];
    }
  }
  // stage the block's contiguous edge-list slice
  int gv0 = (int)nb * 64;
  int st0 = offs[gv0];
  int nedge = offs[gv0 + 63] + cnt[gv0 + 63] - st0;
  int ncap = (nedge < CAPE) ? nedge : CAPE;
  for (int e = t; e < ncap; e += 256) lds_list[e] = list[st0 + e];
  __syncthreads();

  // mean gather: wave w handles nodes w*16..w*16+15; branchless -> 16 loads in flight
  {
    int lane = t & 63, w = t >> 6;
    int stq[16], cq[16];
    float accq[16];
    int cmax = 0;
#pragma unroll
    for (int q = 0; q < 16; ++q) {
      int gv = gv0 + w * 16 + q;
      stq[q] = offs[gv] - st0;
      cq[q] = cnt[gv];
      accq[q] = 0.f;
      cmax = max(cmax, cq[q]);
    }
    int ncl = (nedge > 0) ? (nedge - 1) : 0;
    for (int j = 0; j < cmax; ++j) {
#pragma unroll
      for (int q = 0; q < 16; ++q) {
        bool act = j < cq[q];
        int idx = stq[q] + (act ? j : 0);
        idx = (idx < ncl) ? idx : ncl;
        int sn = (idx < ncap) ? lds_list[idx] : list[st0 + idx];
        float xv = x[(size_t)(sn & 32767) * 64 + lane];
        accq[q] = act ? (accq[q] + xv) : accq[q];
      }
    }
#pragma unroll
    for (int q = 0; q < 16; ++q) {
      int node = w * 16 + q;
      float mval = accq[q] * (1.0f / fmaxf((float)cq[q], 1.0f));
      int col = (((node >> 2) ^ (lane & 15)) << 2) | (node & 3);
      mT[(lane << 6) + col] = mval;
    }
  }
  __syncthreads();

  int tx = t & 15, ty = t >> 4;
  float acc[4][4] = {};
#pragma unroll 4
  for (int k = 0; k < 64; ++k) {
    int s = k & 15;
    int ca = (tx ^ s) << 2, cb = (ty ^ s) << 2;
    const float4 a = *(const float4*)&xT[(k << 6) + ca];
    const float4 m = *(const float4*)&mT[(k << 6) + ca];
    const float4 L = *(const float4*)&wlT[(k << 6) + cb];
    const float4 R = *(const float4*)&wrT[(k << 6) + cb];
    float A[4] = {a.x, a.y, a.z, a.w}, M[4] = {m.x, m.y, m.z, m.w};
    float Lv[4] = {L.x, L.y, L.z, L.w}, Rv[4] = {R.x, R.y, R.z, R.w};
#pragma unroll
    for (int r = 0; r < 4; ++r)
#pragma unroll
      for (int c = 0; c < 4; ++c) acc[r][c] += M[r] * Lv[c] + A[r] * Rv[c];
  }

  float pn = pnbuf[pidx];
  float hv[4][4];
  double sp[4];
#pragma unroll
  for (int r = 0; r < 4; ++r) {
    sp[r] = 0.0;
#pragma unroll
    for (int c = 0; c < 4; ++c) {
      float v = fmaxf(acc[r][c] + bsh[(ty << 2) + c], 0.0f);
      hv[r][c] = v;
      sp[r] += (double)v * (double)psh[(ty << 2) + c];
    }
  }
  __syncthreads();  // reuse smem
  float* hT = smem;                       // 64*68 floats, swizzled col
  double* sred = (double*)(smem + 4608);  // [16][64] doubles
#pragma unroll
  for (int r = 0; r < 4; ++r) {
    int node = (tx << 2) + r;
    int nk = node & 15;
#pragma unroll
    for (int c = 0; c < 4; ++c) hT[node * 68 + (((ty ^ nk) << 2) | c)] = hv[r][c];
    sred[(ty << 6) + node] = sp[r];
  }
  __syncthreads();
  float4* h4 = (float4*)(h + nb * 4096);
  for (int i = t; i < 1024; i += 256) {
    int node = i >> 4, q = i & 15;
    h4[i] = *(const float4*)&hT[node * 68 + ((q ^ (node & 15)) << 2)];
  }
  if (t < 64) {
    double ssum = 0.0;
    for (int g = 0; g < 16; ++g) ssum += sred[(g << 6) + t];
    score[nb * 64 + t] = (float)ssum * pn;
  }
}

// ---------------- GCN ----------------

static __global__ __launch_bounds__(256) void k_gcn_mm(const float* __restrict__ x,
                                                       const float* __restrict__ wT,
                                                       float* __restrict__ h1) {
  __shared__ float smem[4608];
  float* xT = smem;
  int t = threadIdx.x;
  size_t nb = blockIdx.x;
  const float4* x4 = (const float4*)(x + nb * 4096);
  for (int i = t; i < 1024; i += 256) {
    int node = i >> 4, db = (i & 15) << 2;
    float4 a = x4[i];
    float av[4] = {a.x, a.y, a.z, a.w};
    int ng = node >> 2, n0 = node & 3;
#pragma unroll
    for (int j = 0; j < 4; ++j) {
      int d = db + j;
      xT[(d << 6) + (((ng ^ (d & 15)) << 2) | n0)] = av[j];
    }
  }
  __syncthreads();
  int tx = t & 15, ty = t >> 4;
  float acc[4][4] = {};
#pragma unroll 4
  for (int k = 0; k < 64; ++k) {
    int s = k & 15;
    const float4 a = *(const float4*)&xT[(k << 6) + ((tx ^ s) << 2)];
    const float4 W = *(const float4*)&wT[(k << 6) + ((ty ^ s) << 2)];
    float A[4] = {a.x, a.y, a.z, a.w}, Wv[4] = {W.x, W.y, W.z, W.w};
#pragma unroll
    for (int r = 0; r < 4; ++r)
#pragma unroll
      for (int c = 0; c < 4; ++c) acc[r][c] += A[r] * Wv[c];
  }
  __syncthreads();
  float* hT = smem;  // stride 68
#pragma unroll
  for (int r = 0; r < 4; ++r) {
    int node = (tx << 2) + r;
    int nk = node & 15;
#pragma unroll
    for (int c = 0; c < 4; ++c) hT[node * 68 + (((ty ^ nk) << 2) | c)] = acc[r][c];
  }
  __syncthreads();
  float4* h4 = (float4*)(h1 + nb * 4096);
  for (int i = t; i < 1024; i += 256) {
    int node = i >> 4, q = i & 15;
    h4[i] = *(const float4*)&hT[node * 68 + ((q ^ (node & 15)) << 2)];
  }
}

// fused: normalized gather + self term + bias + relu + score
static __global__ void k_gcn_gather(const float* __restrict__ h1, const int* __restrict__ offs,
                                    const int* __restrict__ cnt, const int* __restrict__ list,
                                    const float* __restrict__ b, const float* __restrict__ pvec,
                                    const float* __restrict__ pnbuf, int pidx,
                                    float* __restrict__ h, float* __restrict__ score, int ntot) {
  int lane = threadIdx.x & 63, vl = threadIdx.x >> 6;
  int v = blockIdx.x * 4 + vl;
  if (v >= ntot) return;
  int st = offs[v], c = cnt[v];
  float degv = 1.0f + (float)c;
  float ivd = 1.0f / sqrtf(degv);
  float acc = 0.f;
  for (int j = 0; j < c; ++j) {
    int s = list[st + j];
    float nrm = (1.0f / sqrtf(1.0f + (float)cnt[s])) * ivd;
    acc += h1[(size_t)s * 64 + lane] * nrm;
  }
  float outv = fmaxf(acc + h1[(size_t)v * 64 + lane] * (1.0f / degv) + b[lane], 0.0f);
  h[(size_t)v * 64 + lane] = outv;
  double sc = (double)outv * (double)pvec[lane];
#pragma unroll
  for (int off = 1; off < 64; off <<= 1) sc += __shfl_xor(sc, off);
  if (lane == 0) score[v] = (float)sc * pnbuf[pidx];
}

// ---------------- TopK pool: chunk bitonic (<=1024) + merge-path ----------------

static __global__ void k_chunksort(const float* __restrict__ score,
                                   unsigned long long* __restrict__ runs, int n_per, int k,
                                   int* __restrict__ newidx, int* __restrict__ perm, int single) {
  extern __shared__ unsigned long long sk[];
  int CH = blockDim.x;
  int g0 = blockIdx.x * CH;
  int b = g0 / n_per;
  int i = threadIdx.x;
  int gi = g0 + i;
  int li = gi - b * n_per;
  unsigned u = __float_as_uint(score[gi]);
  unsigned s = (u & 0x80000000u) ? u : ~(u | 0x80000000u);
  sk[i] = ((unsigned long long)s << 32) | (unsigned)li;
  __syncthreads();
  for (int ksz = 2; ksz <= CH; ksz <<= 1) {
    for (int j = ksz >> 1; j > 0; j >>= 1) {
      int ixj = i ^ j;
      if (ixj > i) {
        unsigned long long a = sk[i], c = sk[ixj];
        bool up = ((i & ksz) == 0);
        if ((a > c) == up) {
          sk[i] = c;
          sk[ixj] = a;
        }
      }
      __syncthreads();
    }
  }
  if (!single) {
    runs[gi] = sk[i];
  } else {
    int r = i;
    int idx = (int)(sk[r] & 0xFFFFFFFFu);
    int gidx = b * n_per + idx;
    if (r < k) {
      perm[b * k + r] = gidx;
      newidx[gidx] = b * k + r;
    } else {
      newidx[gidx] = -1;
    }
  }
}

static __global__ void k_merge(const unsigned long long* __restrict__ in,
                               unsigned long long* __restrict__ out, int L, int ntot, int n_per,
                               int k, int* __restrict__ newidx, int* __restrict__ perm,
                               int final) {
  int g = blockIdx.x * 256 + threadIdx.x;
  if (g >= ntot) return;
  unsigned long long key = in[g];
  int pair = g / (2 * L);
  int base = pair * 2 * L;
  int t = g - base;
  const unsigned long long* sib;
  int p;
  if (t < L) {
    sib = in + base + L;
    p = t;
  } else {
    sib = in + base;
    p = t - L;
  }
  int lo = 0, hi = L;
  while (lo < hi) {
    int mid = (lo + hi) >> 1;
    lo = (sib[mid] < key) ? mid + 1 : lo;
    hi = (sib[mid] < key) ? hi : mid;
  }
  int pos = p + lo;
  if (!final) {
    out[base + pos] = key;
  } else {
    int b = base / n_per;
    int idx = (int)(key & 0xFFFFFFFFu);
    int gidx = b * n_per + idx;
    if (pos < k) {
      perm[b * k + pos] = gidx;
      newidx[gidx] = b * k + pos;
    } else {
      newidx[gidx] = -1;
    }
  }
}

// ---------------- fused gather (tanh-scale) + readout partials ----------------

static __global__ __launch_bounds__(1024) void k_gather_ro(
    const float* __restrict__ h, const float* __restrict__ score, const int* __restrict__ perm,
    float* __restrict__ xnew, float* __restrict__ pmax, float* __restrict__ psum) {
  __shared__ float tile[64 * 68];
  __shared__ float pm[16][65], ps[16][65];
  int t = threadIdx.x;
  int node = t >> 4, q = t & 15;
  int nn = blockIdx.x * 64 + node;
  int old = perm[nn];
  float tm = tanhf(score[old]);
  float4 v = *(const float4*)&h[(size_t)old * 64 + q * 4];
  v.x *= tm;
  v.y *= tm;
  v.z *= tm;
  v.w *= tm;
  *(float4*)&xnew[(size_t)nn * 64 + q * 4] = v;
  *(float4*)&tile[node * 68 + ((q ^ (node & 15)) << 2)] = v;
  __syncthreads();
  int slot = t >> 6, d = t & 63;
  int q2 = d >> 2, i3 = d & 3;
  float m = -INFINITY, s = 0.f;
#pragma unroll
  for (int r = 0; r < 4; ++r) {
    int nd = slot * 4 + r;
    float val = tile[nd * 68 + (((q2 ^ (nd & 15)) << 2) | i3)];
    m = fmaxf(m, val);
    s += val;
  }
  pm[slot][d] = m;
  ps[slot][d] = s;
  __syncthreads();
  if (t < 64) {
    float mm = -INFINITY, ss = 0.f;
#pragma unroll
    for (int sl = 0; sl < 16; ++sl) {
      mm = fmaxf(mm, pm[sl][t]);
      ss += ps[sl][t];
    }
    pmax[(size_t)blockIdx.x * 64 + t] = mm;
    psum[(size_t)blockIdx.x * 64 + t] = ss;
  }
}

static __global__ void k_readout_comb(const float* __restrict__ pmax,
                                      const float* __restrict__ psum, float* __restrict__ z,
                                      int k, int nch) {
  int b = blockIdx.x, d = threadIdx.x;
  float m = -INFINITY, s = 0.0f;
  for (int c = 0; c < nch; ++c) {
    m = fmaxf(m, pmax[((size_t)b * nch + c) * 64 + d]);
    s += psum[((size_t)b * nch + c) * 64 + d];
  }
  z[b * 128 + d] += m;
  z[b * 128 + 64 + d] += s / (float)k;
}

// ---------------- MLP + softmax ----------------

static __global__ void k_mlp(const float* __restrict__ z, const float* __restrict__ lw1,
                             const float* __restrict__ lb1, const float* __restrict__ lw2,
                             const float* __restrict__ lb2, const float* __restrict__ lw3,
                             const float* __restrict__ lb3, float* __restrict__ out) {
  __shared__ float zs[128], t1[128], t2[64], t3[256], red[256];
  int b = blockIdx.x, tid = threadIdx.x;
  if (tid < 128) zs[tid] = z[b * 128 + tid];
  __syncthreads();
  if (tid < 128) {
    double a = 0.0;
    for (int d = 0; d < 128; ++d) a += (double)lw1[tid * 128 + d] * (double)zs[d];
    t1[tid] = fmaxf((float)a + lb1[tid], 0.0f);
  }
  __syncthreads();
  if (tid < 64) {
    double a = 0.0;
    for (int d = 0; d < 128; ++d) a += (double)lw2[tid * 128 + d] * (double)t1[d];
    t2[tid] = fmaxf((float)a + lb2[tid], 0.0f);
  }
  __syncthreads();
  {
    double a = 0.0;
    for (int d = 0; d < 64; ++d) a += (double)lw3[tid * 64 + d] * (double)t2[d];
    t3[tid] = (float)a + lb3[tid];
  }
  __syncthreads();
  red[tid] = t3[tid];
  __syncthreads();
  for (int s = 128; s > 0; s >>= 1) {
    if (tid < s) red[tid] = fmaxf(red[tid], red[tid + s]);
    __syncthreads();
  }
  float mx = red[0];
  __syncthreads();
  float e = expf(t3[tid] - mx);
  red[tid] = e;
  __syncthreads();
  for (int s = 128; s > 0; s >>= 1) {
    if (tid < s) red[tid] += red[tid + s];
    __syncthreads();
  }
  out[b * 256 + tid] = e / red[0];
}

// ---------------- launch ----------------

extern "C" void kernel_launch(void* const* d_in, const int* in_sizes, int n_in,
                              void* d_out, int out_size, void* d_ws, size_t ws_size,
                              hipStream_t stream) {
  const float* x0 = (const float*)d_in[0];
  const int* esrc0 = (const int*)d_in[1];
  const int* edst0 = (const int*)d_in[2];
  const float* WL[3] = {(const float*)d_in[3], (const float*)d_in[6], (const float*)d_in[9]};
  const float* BL[3] = {(const float*)d_in[4], (const float*)d_in[7], (const float*)d_in[10]};
  const float* WR[3] = {(const float*)d_in[5], (const float*)d_in[8], (const float*)d_in[11]};
  const float* WG[3] = {(const float*)d_in[12], (const float*)d_in[14], (const float*)d_in[16]};
  const float* BG[3] = {(const float*)d_in[13], (const float*)d_in[15], (const float*)d_in[17]};
  const float* P[6] = {(const float*)d_in[18], (const float*)d_in[19], (const float*)d_in[20],
                       (const float*)d_in[21], (const float*)d_in[22], (const float*)d_in[23]};
  const float* lw1 = (const float*)d_in[24];
  const float* lb1 = (const float*)d_in[25];
  const float* lw2 = (const float*)d_in[26];
  const float* lb2 = (const float*)d_in[27];
  const float* lw3 = (const float*)d_in[28];
  const float* lb3 = (const float*)d_in[29];

  char* ws = (char*)d_ws;
  size_t off = 0;
  auto alloc = [&](size_t bytes) -> void* {
    void* p = ws + off;
    off += (bytes + 255) & ~(size_t)255;
    return p;
  };
  float* hA = (float*)alloc((size_t)65536 * 64 * 4);
  float* hB = (float*)alloc((size_t)32768 * 64 * 4);
  float* mean = (float*)alloc((size_t)65536 * 2 * 4);
  float* tmp = (float*)alloc((size_t)8192 * 64 * 4);
  float* score = (float*)alloc((size_t)65536 * 4);
  int* newidx = (int*)alloc((size_t)65536 * 4);
  int* perm = (int*)alloc((size_t)32768 * 4);
  int* cntA = (int*)alloc((size_t)65536 * 4);
  int* cntB = (int*)alloc((size_t)65536 * 4);
  int* offsA = (int*)alloc((size_t)65536 * 4);
  int* offsB = (int*)alloc((size_t)65536 * 4);
  int* cursor = (int*)alloc((size_t)65536 * 4);
  int* bsum = (int*)alloc((size_t)64 * 4);
  int* listA = (int*)alloc((size_t)NE * 4);
  int* listB = (int*)alloc((size_t)NE * 4);
  float* z = (float*)alloc((size_t)16 * 128 * 4);
  float* pmax = (float*)alloc((size_t)NB * 32 * 64 * 4);
  float* psum = (float*)alloc((size_t)NB * 32 * 64 * 4);
  unsigned long long* keyA = (unsigned long long*)alloc((size_t)65536 * 8);
  unsigned long long* keyB = (unsigned long long*)alloc((size_t)65536 * 8);
  float* pnbuf = (float*)alloc((size_t)64 * 4);
  float* wp = (float*)alloc((size_t)7 * 4096 * 4);
  if (off > ws_size) return;  // workspace too small — bail

  auto scan = [&](int* cntp, int* offsp, int* curp, int n) {
    int nblk = (n + 1023) / 1024;
    k_scan1<<<nblk, 256, 0, stream>>>(cntp, offsp, bsum, n);
    k_scan2<<<1, 64, 0, stream>>>(bsum, nblk);
    k_scan3<<<(n + 255) / 256, 256, 0, stream>>>(offsp, curp, bsum, n);
  };

  hipMemsetAsync(z, 0, 16 * 128 * 4, stream);
  k_pnorm<<<6, 64, 0, stream>>>(P[0], P[1], P[2], P[3], P[4], P[5], pnbuf);
  k_wprep<<<7, 256, 0, stream>>>(WL[1], WR[1], WL[2], WR[2], WG[0], WG[1], WG[2], wp);

  // build layer-0 CSR (dst-sorted src lists)
  hipMemsetAsync(cntA, 0, (size_t)65536 * 4, stream);
  k_count<<<NE / 256, 256, 0, stream>>>(edst0, cntA);
  scan(cntA, offsA, cursor, 65536);
  k_fill0<<<NE / 256, 256, 0, stream>>>(esrc0, edst0, cursor, listA);

  const float* xcur = x0;
  int* ccnt = cntA;
  int* coffs = offsA;
  int* clist = listA;

  for (int i = 0; i < 6; ++i) {
    int n_per = N0 >> i;
    int ntot = NB * n_per;
    int k = n_per >> 1;

    if (i == 0) {
      k_sage_gather2<<<(ntot + 255) / 256, 256, 0, stream>>>(xcur, coffs, ccnt, clist, mean, ntot);
      k_sage0<<<(ntot + 15) / 16, 256, 0, stream>>>(xcur, mean, WL[0], BL[0], WR[0], P[0], pnbuf,
                                                    hA, score, ntot);
    } else if (i < 3) {
      const float* wlp = wp + (size_t)((i - 1) * 2 + 0) * 4096;
      const float* wrp = wp + (size_t)((i - 1) * 2 + 1) * 4096;
      k_sage_mm<<<ntot / 64, 256, 0, stream>>>(xcur, coffs, ccnt, clist, wlp, BL[i], wrp, P[i],
                                               pnbuf, i, hA, score);
    } else {
      int g = i - 3;
      k_gcn_mm<<<ntot / 64, 256, 0, stream>>>(xcur, wp + (size_t)(4 + g) * 4096, tmp);
      k_gcn_gather<<<(ntot + 3) / 4, 256, 0, stream>>>(tmp, coffs, ccnt, clist, BG[g], P[i],
                                                       pnbuf, i, hA, score, ntot);
    }

    // pool i: chunk sort (<=1024) + merge-path rounds
    int CH = (n_per < 1024) ? n_per : 1024;
    int single = (CH == n_per) ? 1 : 0;
    k_chunksort<<<ntot / CH, CH, (size_t)CH * 8, stream>>>(score, keyA, n_per, k, newidx, perm,
                                                           single);
    if (!single) {
      unsigned long long* cur = keyA;
      unsigned long long* nxt = keyB;
      for (int L = CH; L * 2 <= n_per; L <<= 1) {
        int fin = (L * 2 == n_per) ? 1 : 0;
        k_merge<<<(ntot + 255) / 256, 256, 0, stream>>>(cur, nxt, L, ntot, n_per, k, newidx, perm,
                                                        fin);
        unsigned long long* t2 = cur;
        cur = nxt;
        nxt = t2;
      }
    }

    int nch = k / 64;
    k_gather_ro<<<NB * nch, 1024, 0, stream>>>(hA, score, perm, hB, pmax, psum);

    if (i < 5) {
      int newn = NB * k;
      int* ncnt = (i & 1) ? cntA : cntB;
      int* noffs = (i & 1) ? offsA : offsB;
      int* nlist = (i & 1) ? listA : listB;
      k_newcount<<<(newn + 255) / 256, 256, 0, stream>>>(perm, coffs, ccnt, clist, newidx, ncnt,
                                                         newn);
      scan(ncnt, noffs, nullptr, newn);
      k_newfill<<<(newn + 255) / 256, 256, 0, stream>>>(perm, coffs, ccnt, clist, newidx, noffs,
                                                        nlist, newn);
      ccnt = ncnt;
      coffs = noffs;
      clist = nlist;
    }

    k_readout_comb<<<NB, 64, 0, stream>>>(pmax, psum, z, k, nch);
    xcur = hB;
  }

  k_mlp<<<NB, 256, 0, stream>>>(z, lw1, lb1, lw2, lb2, lw3, lb3, (float*)d_out);
}

// Round 12
// 351.641 us; speedup vs baseline: 1.6663x; 1.1414x over previous
//
#include <hip/hip_runtime.h>
#include <math.h>

#define NB 16
#define N0 4096
#define NE 524288
#define CAPE 1280

// ---------------- CSR build (layer 0, atomic int cursor only) ----------------

static __global__ void k_count(const int* __restrict__ dst, int* __restrict__ cnt) {
  int e = blockIdx.x * 256 + threadIdx.x;
  if (e >= NE) return;
  atomicAdd(&cnt[dst[e]], 1);
}

static __global__ void k_fill0(const int* __restrict__ src, const int* __restrict__ dst,
                               int* __restrict__ cursor, int* __restrict__ list) {
  int e = blockIdx.x * 256 + threadIdx.x;
  if (e >= NE) return;
  int d = dst[e];
  int slot = atomicAdd(&cursor[d], 1);
  list[slot] = src[e];
}

// ---------------- exclusive scan (scan1 + scan3-with-inline-bsum-prefix) ----------------

static __global__ void k_scan1(const int* __restrict__ in, int* __restrict__ out,
                               int* __restrict__ bsum, int n) {
  __shared__ int ts[256];
  int base = blockIdx.x * 1024 + threadIdx.x * 4;
  int a0 = (base + 0 < n) ? in[base + 0] : 0;
  int a1 = (base + 1 < n) ? in[base + 1] : 0;
  int a2 = (base + 2 < n) ? in[base + 2] : 0;
  int a3 = (base + 3 < n) ? in[base + 3] : 0;
  int s = a0 + a1 + a2 + a3;
  ts[threadIdx.x] = s;
  __syncthreads();
  for (int off = 1; off < 256; off <<= 1) {
    int v = (threadIdx.x >= off) ? ts[threadIdx.x - off] : 0;
    __syncthreads();
    ts[threadIdx.x] += v;
    __syncthreads();
  }
  int excl = ts[threadIdx.x] - s;
  if (base + 0 < n) out[base + 0] = excl;
  excl += a0;
  if (base + 1 < n) out[base + 1] = excl;
  excl += a1;
  if (base + 2 < n) out[base + 2] = excl;
  excl += a2;
  if (base + 3 < n) out[base + 3] = excl;
  if (threadIdx.x == 255) bsum[blockIdx.x] = ts[255];
}

// adds block offsets (prefix of bsum computed in-kernel by wave 0); optional dual write
static __global__ void k_scan3(int* __restrict__ out, int* __restrict__ out2,
                               const int* __restrict__ bsum, int n, int nblk) {
  __shared__ int sb[64];
  int t = threadIdx.x;
  if (t < 64) {
    int v = (t < nblk) ? bsum[t] : 0;
    int p = v;
    for (int off = 1; off < 64; off <<= 1) {
      int u = __shfl_up(p, off);
      if (t >= off) p += u;
    }
    sb[t] = p - v;
  }
  __syncthreads();
  int i = blockIdx.x * 256 + t;
  if (i < n) {
    int v = out[i] + sb[i >> 10];
    out[i] = v;
    if (out2) out2[i] = v;
  }
}

// ---------------- CSR compaction fill (no atomics) ----------------

static __global__ void k_newfill(const int* __restrict__ perm, const int* __restrict__ offs,
                                 const int* __restrict__ cnt, const int* __restrict__ list,
                                 const int* __restrict__ newidx, const int* __restrict__ noffs,
                                 int* __restrict__ nlist, int newn) {
  int nn = blockIdx.x * 256 + threadIdx.x;
  if (nn >= newn) return;
  int old = perm[nn];
  int st = offs[old], c = cnt[old];
  int pos = noffs[nn];
  for (int j = 0; j < c; ++j) {
    int s2 = newidx[list[st + j]];
    if (s2 >= 0) nlist[pos++] = s2;
  }
}

// ---------------- fused pnorm (blocks 0-5) + weight prep (blocks 6-12) ----------------

static __global__ void k_pw(const float* __restrict__ p0, const float* __restrict__ p1,
                            const float* __restrict__ p2, const float* __restrict__ p3,
                            const float* __restrict__ p4, const float* __restrict__ p5,
                            const float* __restrict__ w0, const float* __restrict__ w1,
                            const float* __restrict__ w2, const float* __restrict__ w3,
                            const float* __restrict__ w4, const float* __restrict__ w5,
                            const float* __restrict__ w6, float* __restrict__ pnbuf,
                            float* __restrict__ wp) {
  if (blockIdx.x < 6) {
    if (threadIdx.x >= 64) return;
    const float* pp = p0;
    switch (blockIdx.x) {
      case 1: pp = p1; break;
      case 2: pp = p2; break;
      case 3: pp = p3; break;
      case 4: pp = p4; break;
      case 5: pp = p5; break;
      default: break;
    }
    double v = (double)pp[threadIdx.x];
    v *= v;
#pragma unroll
    for (int off = 1; off < 64; off <<= 1) v += __shfl_xor(v, off);
    if (threadIdx.x == 0) pnbuf[blockIdx.x] = (float)(1.0 / sqrt(v));
  } else {
    int wi = blockIdx.x - 6;
    const float* src = w0;
    switch (wi) {
      case 1: src = w1; break;
      case 2: src = w2; break;
      case 3: src = w3; break;
      case 4: src = w4; break;
      case 5: src = w5; break;
      case 6: src = w6; break;
      default: break;
    }
    float* dst = wp + (size_t)wi * 4096;
    const float4* w4p = (const float4*)src;
    for (int i4 = threadIdx.x; i4 < 1024; i4 += 256) {
      int o = i4 >> 4, db = (i4 & 15) << 2;
      float4 W = w4p[i4];
      float Wv[4] = {W.x, W.y, W.z, W.w};
      int og = o >> 2, o3 = o & 3;
#pragma unroll
      for (int j = 0; j < 4; ++j) {
        int d = db + j;
        dst[(d << 6) + (((og ^ (d & 15)) << 2) | o3)] = Wv[j];
      }
    }
  }
}

// ---------------- SAGE ----------------

static __global__ void k_sage_gather2(const float* __restrict__ x, const int* __restrict__ offs,
                                      const int* __restrict__ cnt, const int* __restrict__ list,
                                      float* __restrict__ mean, int ntot) {
  int v = blockIdx.x * 256 + threadIdx.x;
  if (v >= ntot) return;
  int st = offs[v], c = cnt[v];
  float s0 = 0.f, s1 = 0.f;
  for (int j = 0; j < c; ++j) {
    int s = list[st + j];
    s0 += x[s * 2 + 0];
    s1 += x[s * 2 + 1];
  }
  float inv = 1.0f / fmaxf((float)c, 1.0f);
  mean[v * 2 + 0] = s0 * inv;
  mean[v * 2 + 1] = s1 * inv;
}

// layer-0 SAGE (DIN=2) + fused score (wave butterfly, double)
static __global__ void k_sage0(const float* __restrict__ x, const float* __restrict__ mean,
                               const float* __restrict__ wl, const float* __restrict__ blv,
                               const float* __restrict__ wr, const float* __restrict__ pvec,
                               const float* __restrict__ pnbuf, float* __restrict__ h,
                               float* __restrict__ score, int ntot) {
  __shared__ float wlT[2][65], wrT[2][65];
  if (threadIdx.x < 128) {
    int o = threadIdx.x >> 1, d = threadIdx.x & 1;
    wlT[d][o] = wl[o * 2 + d];
    wrT[d][o] = wr[o * 2 + d];
  }
  __syncthreads();
  int o = threadIdx.x & 63, vl = threadIdx.x >> 6;
  int base = blockIdx.x * 16 + vl * 4;
  float pn = pnbuf[0];
  float psl = pvec[o];
#pragma unroll
  for (int r = 0; r < 4; ++r) {
    int v = base + r;
    if (v >= ntot) break;
    float acc = blv[o] + mean[v * 2 + 0] * wlT[0][o] + mean[v * 2 + 1] * wlT[1][o] +
                x[v * 2 + 0] * wrT[0][o] + x[v * 2 + 1] * wrT[1][o];
    float hval = fmaxf(acc, 0.0f);
    h[(size_t)v * 64 + o] = hval;
    double sc = (double)hval * (double)psl;
#pragma unroll
    for (int off = 1; off < 64; off <<= 1) sc += __shfl_xor(sc, off);
    if (o == 0) score[v] = (float)sc * pn;
  }
}

// Fused SAGE DIN=64, 512 threads (8 waves): XCD swizzle, LDS list staging,
// branchless 8-way ILP gather, 2x4 register-tile GEMM, bias+relu+score epilogue.
static __global__ __launch_bounds__(512) void k_sage_mm(
    const float* __restrict__ x, const int* __restrict__ offs, const int* __restrict__ cnt,
    const int* __restrict__ list, const float* __restrict__ wlT, const float* __restrict__ blv,
    const float* __restrict__ wrT, const float* __restrict__ pvec,
    const float* __restrict__ pnbuf, int pidx, float* __restrict__ h,
    float* __restrict__ score) {
  __shared__ float smem[8192];
  __shared__ float psh[64], bsh[64];
  __shared__ int lds_list[CAPE];
  float* xT = smem;
  float* mT = smem + 4096;
  int t = threadIdx.x;
  size_t nb = (size_t)((blockIdx.x & 7) * (gridDim.x >> 3) + (blockIdx.x >> 3));

  if (t < 64) {
    psh[t] = pvec[t];
    bsh[t] = blv[t];
  }
  const float4* x4 = (const float4*)(x + nb * 4096);
  for (int i = t; i < 1024; i += 512) {
    int node = i >> 4, db = (i & 15) << 2;
    float4 a = x4[i];
    float av[4] = {a.x, a.y, a.z, a.w};
    int ng = node >> 2, n0 = node & 3;
#pragma unroll
    for (int j = 0; j < 4; ++j) {
      int d = db + j;
      xT[(d << 6) + (((ng ^ (d & 15)) << 2) | n0)] = av[j];
    }
  }
  int gv0 = (int)nb * 64;
  int st0 = offs[gv0];
  int nedge = offs[gv0 + 63] + cnt[gv0 + 63] - st0;
  int ncap = (nedge < CAPE) ? nedge : CAPE;
  for (int e = t; e < ncap; e += 512) lds_list[e] = list[st0 + e];
  __syncthreads();

  // gather: wave w (of 8) handles nodes w*8..w*8+7, branchless 8 loads in flight
  {
    int lane = t & 63, w = t >> 6;
    int stq[8], cq[8];
    float accq[8];
    int cmax = 0;
#pragma unroll
    for (int q = 0; q < 8; ++q) {
      int gv = gv0 + w * 8 + q;
      stq[q] = offs[gv] - st0;
      cq[q] = cnt[gv];
      accq[q] = 0.f;
      cmax = max(cmax, cq[q]);
    }
    int ncl = (nedge > 0) ? (nedge - 1) : 0;
    for (int j = 0; j < cmax; ++j) {
#pragma unroll
      for (int q = 0; q < 8; ++q) {
        bool act = j < cq[q];
        int idx = stq[q] + (act ? j : 0);
        idx = (idx < ncl) ? idx : ncl;
        int sn = (idx < ncap) ? lds_list[idx] : list[st0 + idx];
        float xv = x[(size_t)(sn & 32767) * 64 + lane];
        accq[q] = act ? (accq[q] + xv) : accq[q];
      }
    }
#pragma unroll
    for (int q = 0; q < 8; ++q) {
      int node = w * 8 + q;
      float mval = accq[q] * (1.0f / fmaxf((float)cq[q], 1.0f));
      int col = (((node >> 2) ^ (lane & 15)) << 2) | (node & 3);
      mT[(lane << 6) + col] = mval;
    }
  }
  __syncthreads();

  int tx = t & 15, ty = t >> 4;  // tx: col group (4 cols), ty in [0,32): rows 2ty..2ty+1
  int ng = ty >> 1, n0 = (ty & 1) << 1;
  float acc[2][4] = {};
#pragma unroll 4
  for (int k = 0; k < 64; ++k) {
    int s = k & 15;
    int ca = (((ng ^ s) << 2) | n0);
    const float2 a2 = *(const float2*)&xT[(k << 6) + ca];
    const float2 m2 = *(const float2*)&mT[(k << 6) + ca];
    const float4 L = *(const float4*)&wlT[(k << 6) + ((tx ^ s) << 2)];
    const float4 R = *(const float4*)&wrT[(k << 6) + ((tx ^ s) << 2)];
    float A[2] = {a2.x, a2.y}, M[2] = {m2.x, m2.y};
    float Lv[4] = {L.x, L.y, L.z, L.w}, Rv[4] = {R.x, R.y, R.z, R.w};
#pragma unroll
    for (int r = 0; r < 2; ++r)
#pragma unroll
      for (int c = 0; c < 4; ++c) acc[r][c] += M[r] * Lv[c] + A[r] * Rv[c];
  }

  float pn = pnbuf[pidx];
  float hv[2][4];
  double sp[2];
#pragma unroll
  for (int r = 0; r < 2; ++r) {
    sp[r] = 0.0;
#pragma unroll
    for (int c = 0; c < 4; ++c) {
      float v = fmaxf(acc[r][c] + bsh[(tx << 2) + c], 0.0f);
      hv[r][c] = v;
      sp[r] += (double)v * (double)psh[(tx << 2) + c];
    }
  }
  __syncthreads();  // reuse smem
  float* hT = smem;                       // 64*68 floats, swizzled col
  double* sred = (double*)(smem + 4608);  // [16][64] doubles
#pragma unroll
  for (int r = 0; r < 2; ++r) {
    int node = (ty << 1) + r;
    int nk = node & 15;
#pragma unroll
    for (int c = 0; c < 4; ++c) hT[node * 68 + (((tx ^ nk) << 2) | c)] = hv[r][c];
    sred[(tx << 6) + node] = sp[r];
  }
  __syncthreads();
  float4* h4 = (float4*)(h + nb * 4096);
  for (int i = t; i < 1024; i += 512) {
    int node = i >> 4, q = i & 15;
    h4[i] = *(const float4*)&hT[node * 68 + ((q ^ (node & 15)) << 2)];
  }
  if (t < 64) {
    double ssum = 0.0;
    for (int g = 0; g < 16; ++g) ssum += sred[(g << 6) + t];
    score[nb * 64 + t] = (float)ssum * pn;
  }
}

// ---------------- GCN ----------------

static __global__ __launch_bounds__(256) void k_gcn_mm(const float* __restrict__ x,
                                                       const float* __restrict__ wT,
                                                       float* __restrict__ h1) {
  __shared__ float smem[4608];
  float* xT = smem;
  int t = threadIdx.x;
  size_t nb = blockIdx.x;
  const float4* x4 = (const float4*)(x + nb * 4096);
  for (int i = t; i < 1024; i += 256) {
    int node = i >> 4, db = (i & 15) << 2;
    float4 a = x4[i];
    float av[4] = {a.x, a.y, a.z, a.w};
    int ng = node >> 2, n0 = node & 3;
#pragma unroll
    for (int j = 0; j < 4; ++j) {
      int d = db + j;
      xT[(d << 6) + (((ng ^ (d & 15)) << 2) | n0)] = av[j];
    }
  }
  __syncthreads();
  int tx = t & 15, ty = t >> 4;
  float acc[4][4] = {};
#pragma unroll 4
  for (int k = 0; k < 64; ++k) {
    int s = k & 15;
    const float4 a = *(const float4*)&xT[(k << 6) + ((tx ^ s) << 2)];
    const float4 W = *(const float4*)&wT[(k << 6) + ((ty ^ s) << 2)];
    float A[4] = {a.x, a.y, a.z, a.w}, Wv[4] = {W.x, W.y, W.z, W.w};
#pragma unroll
    for (int r = 0; r < 4; ++r)
#pragma unroll
      for (int c = 0; c < 4; ++c) acc[r][c] += A[r] * Wv[c];
  }
  __syncthreads();
  float* hT = smem;  // stride 68
#pragma unroll
  for (int r = 0; r < 4; ++r) {
    int node = (tx << 2) + r;
    int nk = node & 15;
#pragma unroll
    for (int c = 0; c < 4; ++c) hT[node * 68 + (((ty ^ nk) << 2) | c)] = acc[r][c];
  }
  __syncthreads();
  float4* h4 = (float4*)(h1 + nb * 4096);
  for (int i = t; i < 1024; i += 256) {
    int node = i >> 4, q = i & 15;
    h4[i] = *(const float4*)&hT[node * 68 + ((q ^ (node & 15)) << 2)];
  }
}

// fused: normalized gather + self term + bias + relu + score
static __global__ void k_gcn_gather(const float* __restrict__ h1, const int* __restrict__ offs,
                                    const int* __restrict__ cnt, const int* __restrict__ list,
                                    const float* __restrict__ b, const float* __restrict__ pvec,
                                    const float* __restrict__ pnbuf, int pidx,
                                    float* __restrict__ h, float* __restrict__ score, int ntot) {
  int lane = threadIdx.x & 63, vl = threadIdx.x >> 6;
  int v = blockIdx.x * 4 + vl;
  if (v >= ntot) return;
  int st = offs[v], c = cnt[v];
  float degv = 1.0f + (float)c;
  float ivd = 1.0f / sqrtf(degv);
  float acc = 0.f;
  for (int j = 0; j < c; ++j) {
    int s = list[st + j];
    float nrm = (1.0f / sqrtf(1.0f + (float)cnt[s])) * ivd;
    acc += h1[(size_t)s * 64 + lane] * nrm;
  }
  float outv = fmaxf(acc + h1[(size_t)v * 64 + lane] * (1.0f / degv) + b[lane], 0.0f);
  h[(size_t)v * 64 + lane] = outv;
  double sc = (double)outv * (double)pvec[lane];
#pragma unroll
  for (int off = 1; off < 64; off <<= 1) sc += __shfl_xor(sc, off);
  if (lane == 0) score[v] = (float)sc * pnbuf[pidx];
}

// ---------------- TopK pool: chunk bitonic (<=1024) + merge-path ----------------

static __global__ void k_chunksort(const float* __restrict__ score,
                                   unsigned long long* __restrict__ runs, int n_per, int k,
                                   int* __restrict__ newidx, int* __restrict__ perm, int single) {
  extern __shared__ unsigned long long sk[];
  int CH = blockDim.x;
  int g0 = blockIdx.x * CH;
  int b = g0 / n_per;
  int i = threadIdx.x;
  int gi = g0 + i;
  int li = gi - b * n_per;
  unsigned u = __float_as_uint(score[gi]);
  unsigned s = (u & 0x80000000u) ? u : ~(u | 0x80000000u);
  sk[i] = ((unsigned long long)s << 32) | (unsigned)li;
  __syncthreads();
  for (int ksz = 2; ksz <= CH; ksz <<= 1) {
    for (int j = ksz >> 1; j > 0; j >>= 1) {
      int ixj = i ^ j;
      if (ixj > i) {
        unsigned long long a = sk[i], c = sk[ixj];
        bool up = ((i & ksz) == 0);
        if ((a > c) == up) {
          sk[i] = c;
          sk[ixj] = a;
        }
      }
      __syncthreads();
    }
  }
  if (!single) {
    runs[gi] = sk[i];
  } else {
    int r = i;
    int idx = (int)(sk[r] & 0xFFFFFFFFu);
    int gidx = b * n_per + idx;
    if (r < k) {
      perm[b * k + r] = gidx;
      newidx[gidx] = b * k + r;
    } else {
      newidx[gidx] = -1;
    }
  }
}

static __global__ void k_merge(const unsigned long long* __restrict__ in,
                               unsigned long long* __restrict__ out, int L, int ntot, int n_per,
                               int k, int* __restrict__ newidx, int* __restrict__ perm,
                               int final) {
  int g = blockIdx.x * 256 + threadIdx.x;
  if (g >= ntot) return;
  unsigned long long key = in[g];
  int pair = g / (2 * L);
  int base = pair * 2 * L;
  int t = g - base;
  const unsigned long long* sib;
  int p;
  if (t < L) {
    sib = in + base + L;
    p = t;
  } else {
    sib = in + base;
    p = t - L;
  }
  int lo = 0, hi = L;
  while (lo < hi) {
    int mid = (lo + hi) >> 1;
    lo = (sib[mid] < key) ? mid + 1 : lo;
    hi = (sib[mid] < key) ? hi : mid;
  }
  int pos = p + lo;
  if (!final) {
    out[base + pos] = key;
  } else {
    int b = base / n_per;
    int idx = (int)(key & 0xFFFFFFFFu);
    int gidx = b * n_per + idx;
    if (pos < k) {
      perm[b * k + pos] = gidx;
      newidx[gidx] = b * k + pos;
    } else {
      newidx[gidx] = -1;
    }
  }
}

// ---------------- fused gather+readout partials (blocks < G1) + newcount (rest) ----------------

static __global__ __launch_bounds__(1024) void k_pool_post(
    const float* __restrict__ h, const float* __restrict__ score, const int* __restrict__ perm,
    float* __restrict__ xnew, float* __restrict__ pmax, float* __restrict__ psum, int base,
    const int* __restrict__ offs, const int* __restrict__ cnt, const int* __restrict__ list,
    const int* __restrict__ newidx, int* __restrict__ ncnt, int newn, int G1) {
  __shared__ float tile[64 * 68];
  __shared__ float pm[16][65], ps[16][65];
  int t = threadIdx.x;
  if ((int)blockIdx.x >= G1) {
    int nn = ((int)blockIdx.x - G1) * 1024 + t;
    if (nn >= newn) return;
    int old = perm[nn];
    int st = offs[old], c = cnt[old];
    int cc = 0;
    for (int j = 0; j < c; ++j) cc += (newidx[list[st + j]] >= 0);
    ncnt[nn] = cc;
    return;
  }
  int node = t >> 4, q = t & 15;
  int nn = blockIdx.x * 64 + node;
  int old = perm[nn];
  float tm = tanhf(score[old]);
  float4 v = *(const float4*)&h[(size_t)old * 64 + q * 4];
  v.x *= tm;
  v.y *= tm;
  v.z *= tm;
  v.w *= tm;
  *(float4*)&xnew[(size_t)nn * 64 + q * 4] = v;
  *(float4*)&tile[node * 68 + ((q ^ (node & 15)) << 2)] = v;
  __syncthreads();
  int slot = t >> 6, d = t & 63;
  int q2 = d >> 2, i3 = d & 3;
  float m = -INFINITY, s = 0.f;
#pragma unroll
  for (int r = 0; r < 4; ++r) {
    int nd = slot * 4 + r;
    float val = tile[nd * 68 + (((q2 ^ (nd & 15)) << 2) | i3)];
    m = fmaxf(m, val);
    s += val;
  }
  pm[slot][d] = m;
  ps[slot][d] = s;
  __syncthreads();
  if (t < 64) {
    float mm = -INFINITY, ss = 0.f;
#pragma unroll
    for (int sl = 0; sl < 16; ++sl) {
      mm = fmaxf(mm, pm[sl][t]);
      ss += ps[sl][t];
    }
    pmax[(size_t)(base + blockIdx.x) * 64 + t] = mm;
    psum[(size_t)(base + blockIdx.x) * 64 + t] = ss;
  }
}

// ---------------- MLP + softmax (with deferred readout combine) ----------------

static __global__ void k_mlp(const float* __restrict__ pmax, const float* __restrict__ psum,
                             const float* __restrict__ lw1, const float* __restrict__ lb1,
                             const float* __restrict__ lw2, const float* __restrict__ lb2,
                             const float* __restrict__ lw3, const float* __restrict__ lb3,
                             float* __restrict__ out) {
  __shared__ float zs[128], t1[128], t2[64], t3[256], red[256];
  int b = blockIdx.x, tid = threadIdx.x;
  const int baseL[6] = {0, 512, 768, 896, 960, 992};
  const int nchL[6] = {32, 16, 8, 4, 2, 1};
  const int kkL[6] = {2048, 1024, 512, 256, 128, 64};
  if (tid < 64) {
    float zm = 0.f;
    for (int i = 0; i < 6; ++i) {
      float m = -INFINITY;
      for (int c = 0; c < nchL[i]; ++c)
        m = fmaxf(m, pmax[(size_t)(baseL[i] + b * nchL[i] + c) * 64 + tid]);
      zm += m;
    }
    zs[tid] = zm;
  } else if (tid < 128) {
    int d = tid - 64;
    float zsum = 0.f;
    for (int i = 0; i < 6; ++i) {
      float s = 0.f;
      for (int c = 0; c < nchL[i]; ++c)
        s += psum[(size_t)(baseL[i] + b * nchL[i] + c) * 64 + d];
      zsum += s / (float)kkL[i];
    }
    zs[tid] = zsum;
  }
  __syncthreads();
  if (tid < 128) {
    double a = 0.0;
    for (int d = 0; d < 128; ++d) a += (double)lw1[tid * 128 + d] * (double)zs[d];
    t1[tid] = fmaxf((float)a + lb1[tid], 0.0f);
  }
  __syncthreads();
  if (tid < 64) {
    double a = 0.0;
    for (int d = 0; d < 128; ++d) a += (double)lw2[tid * 128 + d] * (double)t1[d];
    t2[tid] = fmaxf((float)a + lb2[tid], 0.0f);
  }
  __syncthreads();
  {
    double a = 0.0;
    for (int d = 0; d < 64; ++d) a += (double)lw3[tid * 64 + d] * (double)t2[d];
    t3[tid] = (float)a + lb3[tid];
  }
  __syncthreads();
  red[tid] = t3[tid];
  __syncthreads();
  for (int s = 128; s > 0; s >>= 1) {
    if (tid < s) red[tid] = fmaxf(red[tid], red[tid + s]);
    __syncthreads();
  }
  float mx = red[0];
  __syncthreads();
  float e = expf(t3[tid] - mx);
  red[tid] = e;
  __syncthreads();
  for (int s = 128; s > 0; s >>= 1) {
    if (tid < s) red[tid] += red[tid + s];
    __syncthreads();
  }
  out[b * 256 + tid] = e / red[0];
}

// ---------------- launch ----------------

extern "C" void kernel_launch(void* const* d_in, const int* in_sizes, int n_in,
                              void* d_out, int out_size, void* d_ws, size_t ws_size,
                              hipStream_t stream) {
  const float* x0 = (const float*)d_in[0];
  const int* esrc0 = (const int*)d_in[1];
  const int* edst0 = (const int*)d_in[2];
  const float* WL[3] = {(const float*)d_in[3], (const float*)d_in[6], (const float*)d_in[9]};
  const float* BL[3] = {(const float*)d_in[4], (const float*)d_in[7], (const float*)d_in[10]};
  const float* WR[3] = {(const float*)d_in[5], (const float*)d_in[8], (const float*)d_in[11]};
  const float* WG[3] = {(const float*)d_in[12], (const float*)d_in[14], (const float*)d_in[16]};
  const float* BG[3] = {(const float*)d_in[13], (const float*)d_in[15], (const float*)d_in[17]};
  const float* P[6] = {(const float*)d_in[18], (const float*)d_in[19], (const float*)d_in[20],
                       (const float*)d_in[21], (const float*)d_in[22], (const float*)d_in[23]};
  const float* lw1 = (const float*)d_in[24];
  const float* lb1 = (const float*)d_in[25];
  const float* lw2 = (const float*)d_in[26];
  const float* lb2 = (const float*)d_in[27];
  const float* lw3 = (const float*)d_in[28];
  const float* lb3 = (const float*)d_in[29];

  char* ws = (char*)d_ws;
  size_t off = 0;
  auto alloc = [&](size_t bytes) -> void* {
    void* p = ws + off;
    off += (bytes + 255) & ~(size_t)255;
    return p;
  };
  float* hA = (float*)alloc((size_t)65536 * 64 * 4);
  float* hB = (float*)alloc((size_t)32768 * 64 * 4);
  float* mean = (float*)alloc((size_t)65536 * 2 * 4);
  float* tmp = (float*)alloc((size_t)8192 * 64 * 4);
  float* score = (float*)alloc((size_t)65536 * 4);
  int* newidx = (int*)alloc((size_t)65536 * 4);
  int* perm = (int*)alloc((size_t)32768 * 4);
  int* cntA = (int*)alloc((size_t)65536 * 4);
  int* cntB = (int*)alloc((size_t)65536 * 4);
  int* offsA = (int*)alloc((size_t)65536 * 4);
  int* offsB = (int*)alloc((size_t)65536 * 4);
  int* cursor = (int*)alloc((size_t)65536 * 4);
  int* bsum = (int*)alloc((size_t)64 * 4);
  int* listA = (int*)alloc((size_t)NE * 4);
  int* listB = (int*)alloc((size_t)NE * 4);
  float* pmax = (float*)alloc((size_t)1024 * 64 * 4);
  float* psum = (float*)alloc((size_t)1024 * 64 * 4);
  unsigned long long* keyA = (unsigned long long*)alloc((size_t)65536 * 8);
  unsigned long long* keyB = (unsigned long long*)alloc((size_t)65536 * 8);
  float* pnbuf = (float*)alloc((size_t)64 * 4);
  float* wp = (float*)alloc((size_t)7 * 4096 * 4);
  if (off > ws_size) return;  // workspace too small — bail

  auto scan = [&](int* cntp, int* offsp, int* curp, int n) {
    int nblk = (n + 1023) / 1024;
    k_scan1<<<nblk, 256, 0, stream>>>(cntp, offsp, bsum, n);
    k_scan3<<<(n + 255) / 256, 256, 0, stream>>>(offsp, curp, bsum, n, nblk);
  };

  k_pw<<<13, 256, 0, stream>>>(P[0], P[1], P[2], P[3], P[4], P[5], WL[1], WR[1], WL[2], WR[2],
                               WG[0], WG[1], WG[2], pnbuf, wp);

  // build layer-0 CSR (dst-sorted src lists)
  hipMemsetAsync(cntA, 0, (size_t)65536 * 4, stream);
  k_count<<<NE / 256, 256, 0, stream>>>(edst0, cntA);
  scan(cntA, offsA, cursor, 65536);
  k_fill0<<<NE / 256, 256, 0, stream>>>(esrc0, edst0, cursor, listA);

  const float* xcur = x0;
  int* ccnt = cntA;
  int* coffs = offsA;
  int* clist = listA;
  const int baseL[6] = {0, 512, 768, 896, 960, 992};

  for (int i = 0; i < 6; ++i) {
    int n_per = N0 >> i;
    int ntot = NB * n_per;
    int k = n_per >> 1;

    if (i == 0) {
      k_sage_gather2<<<(ntot + 255) / 256, 256, 0, stream>>>(xcur, coffs, ccnt, clist, mean, ntot);
      k_sage0<<<(ntot + 15) / 16, 256, 0, stream>>>(xcur, mean, WL[0], BL[0], WR[0], P[0], pnbuf,
                                                    hA, score, ntot);
    } else if (i < 3) {
      const float* wlp = wp + (size_t)((i - 1) * 2 + 0) * 4096;
      const float* wrp = wp + (size_t)((i - 1) * 2 + 1) * 4096;
      k_sage_mm<<<ntot / 64, 512, 0, stream>>>(xcur, coffs, ccnt, clist, wlp, BL[i], wrp, P[i],
                                               pnbuf, i, hA, score);
    } else {
      int g = i - 3;
      k_gcn_mm<<<ntot / 64, 256, 0, stream>>>(xcur, wp + (size_t)(4 + g) * 4096, tmp);
      k_gcn_gather<<<(ntot + 3) / 4, 256, 0, stream>>>(tmp, coffs, ccnt, clist, BG[g], P[i],
                                                       pnbuf, i, hA, score, ntot);
    }

    // pool i: chunk sort (<=1024) + merge-path rounds
    int CH = (n_per < 1024) ? n_per : 1024;
    int single = (CH == n_per) ? 1 : 0;
    k_chunksort<<<ntot / CH, CH, (size_t)CH * 8, stream>>>(score, keyA, n_per, k, newidx, perm,
                                                           single);
    if (!single) {
      unsigned long long* cur = keyA;
      unsigned long long* nxt = keyB;
      for (int L = CH; L * 2 <= n_per; L <<= 1) {
        int fin = (L * 2 == n_per) ? 1 : 0;
        k_merge<<<(ntot + 255) / 256, 256, 0, stream>>>(cur, nxt, L, ntot, n_per, k, newidx, perm,
                                                        fin);
        unsigned long long* t2 = cur;
        cur = nxt;
        nxt = t2;
      }
    }

    int nch = k / 64;
    int G1 = NB * nch;
    int newn = (i < 5) ? NB * k : 0;
    int* ncnt = (i & 1) ? cntA : cntB;
    int G2 = (newn > 0) ? (newn + 1023) / 1024 : 0;
    k_pool_post<<<G1 + G2, 1024, 0, stream>>>(hA, score, perm, hB, pmax, psum, baseL[i], coffs,
                                              ccnt, clist, newidx, ncnt, newn, G1);

    if (i < 5) {
      int* noffs = (i & 1) ? offsA : offsB;
      int* nlist = (i & 1) ? listA : listB;
      scan(ncnt, noffs, nullptr, newn);
      k_newfill<<<(newn + 255) / 256, 256, 0, stream>>>(perm, coffs, ccnt, clist, newidx, noffs,
                                                        nlist, newn);
      ccnt = ncnt;
      coffs = noffs;
      clist = nlist;
    }

    xcur = hB;
  }

  k_mlp<<<NB, 256, 0, stream>>>(pmax, psum, lw1, lb1, lw2, lb2, lw3, lb3, (float*)d_out);
}